// Round 17
// baseline (932.050 us; speedup 1.0000x reference)
//
#include <hip/hip_runtime.h>
#include <math.h>

#define T_   4
#define B_   32
#define C_   384
#define N_   196
#define HID_ 1536
#define NH_  12
#define DH_  32
#define NCOL (B_*N_)            // 6272 columns j=(b,n)
#define NJT  (NCOL/16)          // 392 j-tiles of 16
#define NSLC 98                 // attn n-slice (N_/2)
#define THRESH 2e-3f            // certainty margin (worst-case MFMA-path err ~3e-4)
#define FCAP (1u<<17)

typedef unsigned char u8;
typedef unsigned int  u32;
using bf16x8 = __attribute__((ext_vector_type(8))) short;
using f32x4  = __attribute__((ext_vector_type(4))) float;

__device__ __forceinline__ float bfbits2f(short u) {
    union { u32 i; float f; } c; c.i = ((u32)(unsigned short)u) << 16; return c.f;
}
__device__ __forceinline__ short f2bf(float f) {       // RNE f32 -> bf16 bits
    u32 b = __float_as_uint(f);
    return (short)((b + 0x7FFFu + ((b >> 16) & 1u)) >> 16);
}

__device__ __forceinline__ void gload_lds16(const short* g, short* l) {
    __builtin_amdgcn_global_load_lds(
        (const __attribute__((address_space(1))) void*)g,
        (__attribute__((address_space(3))) void*)l, 16, 0, 0);
}

__global__ void zero_counters(u32* cnt) { if (threadIdx.x < 4) cnt[threadIdx.x] = 0; }

// ---------------------------------------------------------------------------
// Weight split -> fragment-major, hi/lo ADJACENT (r14-proven):
// A[((ot*nkb + kb)*2 + s)*512 + (ol + 16*part)*8 + elem]
// ---------------------------------------------------------------------------
__global__ void wprep(const float* __restrict__ W, short* __restrict__ HL,
                      int c_out, int c_in)
{
    const int ng = c_out * (c_in >> 3);
    int i = blockIdx.x * 256 + threadIdx.x;
    if (i >= ng) return;
    const int o = i / (c_in >> 3);
    const int c = (i % (c_in >> 3)) << 3;
    const int ot = o >> 4, ol = o & 15;
    const int kb = c >> 5, part = (c & 31) >> 3;
    const int nkb = c_in >> 5;
    const size_t fp = (((size_t)(ot * nkb + kb) * 2) << 9) + (size_t)((ol + (part << 4)) << 3);
    short h8[8], l8[8];
#pragma unroll
    for (int k = 0; k < 8; ++k) {
        float f = W[(size_t)o * c_in + c + k];
        short h = f2bf(f);
        h8[k] = h;
        l8[k] = f2bf(f - bfbits2f(h));
    }
    *(bf16x8*)&HL[fp]       = *(bf16x8*)h8;
    *(bf16x8*)&HL[fp + 512] = *(bf16x8*)l8;
}

// ---------------------------------------------------------------------------
// Transpose [tb][c][n] -> fragment-major B superchunks (r14-proven):
//   SPL=2: B[((jt*nkb+kb)*8 + t*2 + s)*512 + (jl+16*part)*8 + elem]
//   SPL=1: B[((jt*nkb+kb)*4 + t    )*512 + ...]  (spikes, hi only, exact)
// + optional exact linear copies for the f64 fixups.
// ---------------------------------------------------------------------------
template<int MODE>
__global__ __launch_bounds__(256) void tpose(
    const void* __restrict__ src, const u8* __restrict__ Sadd,
    short* __restrict__ HL,
    float* __restrict__ F, u8* __restrict__ SPTo,
    int c_tot, int nct)
{
    __shared__ float lds[64][197];
    __shared__ u8 slds[MODE == 0 ? 64 : 1][MODE == 0 ? 197 : 1];
    const int tid = threadIdx.x;
    const int tb = blockIdx.x / nct;
    const int ct = blockIdx.x % nct;
    const int t = tb / B_, b = tb % B_;
    const int nkb = c_tot >> 5;
    const float* Xf = (const float*)src;
    const u8*    Xb = (const u8*)src;

    for (int i = tid; i < 64 * N_; i += 256) {
        int c = i / N_, n = i % N_;
        size_t g = ((size_t)tb * c_tot + ct * 64 + c) * N_ + n;
        if (MODE == 0) {
            float v = Xf[g];
            u8 s = Sadd ? Sadd[g] : (u8)0;
            lds[c][n] = v + (float)s;
            slds[c][n] = s;
        } else {
            lds[c][n] = (float)Xb[g];
        }
    }
    __syncthreads();

    for (int i = tid; i < N_ * 8; i += 256) {
        const int n = i >> 3;
        const int c_loc = (i & 7) << 3;
        const int c = ct * 64 + c_loc;
        const int j = b * N_ + n;
        const int jt = j >> 4, jl = j & 15;
        const int kb = c >> 5, part = (c & 31) >> 3;
        const size_t pos = (size_t)((jl + (part << 4)) << 3);
        short h8[8], l8[8];
        float f8[8];
#pragma unroll
        for (int k = 0; k < 8; ++k) {
            float f = lds[c_loc + k][n];
            f8[k] = f;
            short h = f2bf(f);
            h8[k] = h;
            if (MODE == 0) l8[k] = f2bf(f - bfbits2f(h));
        }
        if (MODE == 0) {
            const size_t fp = (((size_t)(jt * nkb + kb) * 8 + t * 2) << 9) + pos;
            *(bf16x8*)&HL[fp]       = *(bf16x8*)h8;
            *(bf16x8*)&HL[fp + 512] = *(bf16x8*)l8;
            if (F) {
                const size_t lp = ((size_t)(t * NCOL + j)) * c_tot + c;
                *(float4*)&F[lp]     = *(float4*)&f8[0];
                *(float4*)&F[lp + 4] = *(float4*)&f8[4];
            }
            if (SPTo) {
                const size_t lp = ((size_t)(t * NCOL + j)) * c_tot + c;
#pragma unroll
                for (int k = 0; k < 8; ++k) SPTo[lp + k] = slds[c_loc + k][n];
            }
        } else {
            const size_t fp = (((size_t)(jt * nkb + kb) * 4 + t) << 9) + pos;
            *(bf16x8*)&HL[fp] = *(bf16x8*)h8;
        }
    }
}

// ---------------------------------------------------------------------------
// MFMA GEMM + BN + LIF + flagging.  C[o,j,t] = sum_c W[o,c] X[t,j,c].
// r16: OB2 output-tile widening (128o x 64j for OB2=2).
// r17: OM=0 epilogue stores compacted — spikes written to the (dead) a_lds
// as a [t][o_local][j_local] u8 tile, then flushed as coalesced u32 stores
// (4 consecutive j per dword; 196%4==0 so dwords never cross a batch).
// Store instructions per thread: 128 -> 32 (OB2=2).  Global spike bytes are
// bit-identical to r16 — only the store shape changes.
// D: col = lane&15, row = (lane>>4)*4 + reg  [m89-verified].
// ---------------------------------------------------------------------------
template<int SPLITS, int OM, int NZ, int OB2>
__global__ __launch_bounds__(256, 2) void gemm_lif(
    const short* __restrict__ BHL,
    const short* __restrict__ WA0, const short* __restrict__ WA1, const short* __restrict__ WA2,
    const float* __restrict__ cb0, const float* __restrict__ cb1, const float* __restrict__ cb2,
    const float* __restrict__ bn0, const float* __restrict__ bn1, const float* __restrict__ bn2,
    const float* __restrict__ lw0, const float* __restrict__ lw1, const float* __restrict__ lw2,
    u8* S0, u8* S1, u8* S2,
    const float* __restrict__ xres, const u8* __restrict__ sres, float* __restrict__ out,
    u32* __restrict__ cnt, u32* __restrict__ flags,
    int c_out, int c_in, int nob)
{
    constexpr int NOS = 4 * OB2;                   // o-subtiles per thread
    __shared__ short a_lds[2 * NOS * 2 * 512];     // OB2=2: 32KB, OB2=1: 16KB
    const int tid = threadIdx.x;
    const int w = tid >> 6, l = tid & 63;

    // ---- bijective XCD-contiguity swizzle (8 XCDs, m204 formula) ----
    const u32 nwg = gridDim.x;
    const u32 q = nwg >> 3, r = nwg & 7;
    const u32 xcd = blockIdx.x & 7, off = blockIdx.x >> 3;
    const u32 id = (xcd < r ? xcd * (q + 1) : r * (q + 1) + (xcd - r) * q) + off;

    const int mt  = (int)(id / (u32)(nob * NZ));
    const int rem = (int)(id % (u32)(nob * NZ));
    const int z  = (NZ == 1) ? 0 : (rem % NZ);
    const int ob = (NZ == 1) ? rem : (rem / NZ);

    const short* WA  = (z == 0) ? WA0 : ((z == 1) ? WA1 : WA2);
    const float* cb  = (z == 0) ? cb0 : ((z == 1) ? cb1 : cb2);
    const float* bnp = (z == 0) ? bn0 : ((z == 1) ? bn1 : bn2);
    const float* lw  = (z == 0) ? lw0 : ((z == 1) ? lw1 : lw2);
    u8* SOUT         = (z == 0) ? S0  : ((z == 1) ? S1  : S2);

    const int nkb = c_in >> 5;
    const int jt = mt * 4 + w;
    const int j  = jt * 16 + (l & 15);
    const int obBase = ob * (NOS * 16);

    f32x4 acc[4][NOS];
#pragma unroll
    for (int t = 0; t < 4; ++t)
#pragma unroll
        for (int os = 0; os < NOS; ++os)
            acc[t][os] = (f32x4){0.f, 0.f, 0.f, 0.f};

    // B superchunk base: per kb, 8 (or 4) consecutive 1KB chunks
    const short* bbase = BHL + (size_t)l * 8;

    // ping/pong B fragment sets (statically named; no dynamic indexing)
    bf16x8 bhA[4], blA[4], bhB[4], blB[4];

    auto LOADB = [&](int kb, bf16x8* bh, bf16x8* bl) {
        const short* p = bbase + (((size_t)jt * nkb + kb) << (SPLITS == 2 ? 12 : 11));
#pragma unroll
        for (int t = 0; t < 4; ++t) {
            if (SPLITS == 2) {
                bh[t] = *(const bf16x8*)(p + ((size_t)(t * 2)     << 9));
                bl[t] = *(const bf16x8*)(p + ((size_t)(t * 2 + 1) << 9));
            } else {
                bh[t] = *(const bf16x8*)(p + ((size_t)t << 9));
            }
        }
    };
    // stage A(kb): NOS*2 chunks of 1KB; wave w stages NOS/2
    auto STAGE = [&](int kb, int p) {
#pragma unroll
        for (int cc = 0; cc < 2 * OB2; ++cc) {
            const int ch = w * (2 * OB2) + cc;
            const int os = ch >> 1, split = ch & 1;
            const short* src = WA
                + ((((size_t)(ob * NOS + os) * nkb + kb) * 2 + split) << 9)
                + (size_t)l * 8;
            gload_lds16(src, &a_lds[(size_t)(p * NOS * 2 + ch) * 512 + (size_t)l * 8]);
        }
    };
    auto COMPUTE = [&](int p, const bf16x8* bh, const bf16x8* bl) {
#pragma unroll
        for (int os = 0; os < NOS; ++os) {
            const bf16x8 ah = *(const bf16x8*)&a_lds[(size_t)(p * NOS * 2 + os * 2    ) * 512 + (size_t)l * 8];
            const bf16x8 al = *(const bf16x8*)&a_lds[(size_t)(p * NOS * 2 + os * 2 + 1) * 512 + (size_t)l * 8];
#pragma unroll
            for (int t = 0; t < 4; ++t) {
                acc[t][os] = __builtin_amdgcn_mfma_f32_16x16x32_bf16(ah, bh[t], acc[t][os], 0, 0, 0);
                acc[t][os] = __builtin_amdgcn_mfma_f32_16x16x32_bf16(al, bh[t], acc[t][os], 0, 0, 0);
                if (SPLITS == 2)   // lo x lo term dropped (r11)
                    acc[t][os] = __builtin_amdgcn_mfma_f32_16x16x32_bf16(ah, bl[t], acc[t][os], 0, 0, 0);
            }
        }
    };

    STAGE(0, 0);
    LOADB(0, bhA, blA);
    __syncthreads();                       // buf0 ready
    for (int kb = 0; kb < nkb; kb += 2) {  // nkb is even (12 or 48)
        STAGE(kb + 1, 1);
        LOADB(kb + 1, bhB, blB);
        COMPUTE(0, bhA, blA);
        __syncthreads();                   // buf1 ready; buf0 free
        if (kb + 2 < nkb) {
            STAGE(kb + 2, 0);
            LOADB(kb + 2, bhA, blA);
        }
        COMPUTE(1, bhB, blB);
        __syncthreads();                   // buf0 ready; buf1 free
    }

    const float tau = 1.0f / (1.0f + expf(-lw[0]));
    const size_t per_t = (size_t)B_ * c_out * N_;
    const int jb = j / N_, jn = j % N_;
    // r17: spike tile in (now-dead) a_lds: [t][o_local (NOS*16)][j_local (64)]
    u8* s_tile = (u8*)a_lds;
    const int jl_loc = w * 16 + (l & 15);

#pragma unroll
    for (int os = 0; os < NOS; ++os) {
#pragma unroll
        for (int r2 = 0; r2 < 4; ++r2) {
            const int o_loc = os * 16 + (l >> 4) * 4 + r2;
            const int o = obBase + o_loc;
            const float g  = bnp[o];
            const float be = bnp[c_out + o];
            const float mm = bnp[2 * c_out + o];
            const float vv = bnp[3 * c_out + o];
            const float inv   = g / sqrtf(vv + 1e-5f);
            const float shift = be - mm * inv;
            const float cbv   = cb ? cb[o] : 0.0f;
            const size_t idx0 = ((size_t)jb * c_out + o) * N_ + jn;
            float v = 0.0f;
            bool flag = false;
#pragma unroll
            for (int t = 0; t < 4; ++t) {
                const float yv = (acc[t][os][r2] + cbv) * inv + shift;
                const float h  = v + (yv - v) * tau;
                const float sp = (h >= 1.0f) ? 1.0f : 0.0f;
                flag = flag || (fabsf(h - 1.0f) < THRESH);
                v = h * (1.0f - sp);
                if (OM == 0) {
                    s_tile[((t * NOS * 16) + o_loc) * 64 + jl_loc] = (u8)sp;
                } else {
                    const size_t idx = (size_t)t * per_t + idx0;
                    out[idx] = (float)((double)xres[idx] + (double)sres[idx] + (double)sp);
                }
            }
            if (flag) {
                u32 p2 = atomicAdd(cnt, 1u);
                if (p2 < FCAP) flags[p2] = ((u32)(z * c_out + o)) * (u32)NCOL + (u32)j;
            }
        }
    }

    if (OM == 0) {
        __syncthreads();                   // spike tile complete
        // coalesced flush: NOS*1024 u32 total; NOS*4 per thread
#pragma unroll
        for (int k = 0; k < NOS * 4; ++k) {
            const int i4 = tid + 256 * k;
            const int t  = i4 / (NOS * 256);
            const int r3 = i4 % (NOS * 256);
            const int o_loc = r3 >> 4;
            const int col4  = r3 & 15;
            const int jj  = mt * 64 + col4 * 4;      // 4-aligned, 196%4==0
            const int jb2 = jj / N_, jn2 = jj % N_;
            const int o   = obBase + o_loc;
            const u32 val = *(const u32*)&s_tile[((t * NOS * 16) + o_loc) * 64 + col4 * 4];
            *(u32*)&SOUT[(size_t)t * per_t + ((size_t)jb2 * c_out + o) * N_ + jn2] = val;
        }
    }
}

// ---------------------------------------------------------------------------
// f64 fixup (decision math = r5/r7-proven all-f64 path).
// IN_MODE 0: linear f32 XT; 1: fragment-major bf16 spikes (r14 layout);
// 2: linear f32 XT + linear u8 SPT.
// ---------------------------------------------------------------------------
template<int IN_MODE, int OM>
__global__ __launch_bounds__(256) void fixup_t(
    const void* __restrict__ XT, const u8* __restrict__ SPT,
    const float* __restrict__ W0, const float* __restrict__ W1, const float* __restrict__ W2,
    const float* __restrict__ cb0, const float* __restrict__ cb1, const float* __restrict__ cb2,
    const float* __restrict__ bn0, const float* __restrict__ bn1, const float* __restrict__ bn2,
    const float* __restrict__ lw0, const float* __restrict__ lw1, const float* __restrict__ lw2,
    u8* S0, u8* S1, u8* S2,
    const float* __restrict__ xres, const u8* __restrict__ sres, float* out,
    const u32* __restrict__ cnt, const u32* __restrict__ flags,
    int c_out, int c_in)
{
    const int lane = threadIdx.x & 63;
    const int wid  = (blockIdx.x * 256 + threadIdx.x) >> 6;
    const int nw   = (gridDim.x * 256) >> 6;
    u32 nrec = *cnt;
    if (nrec > FCAP) nrec = FCAP;

    const float* XTf = (const float*)XT;
    const short* XTs = (const short*)XT;
    const int nkb = c_in >> 5;

    for (u32 r = wid; r < nrec; r += nw) {
        const u32 rec = flags[r];
        const int j  = (int)(rec % (u32)NCOL);
        const u32 zo = rec / (u32)NCOL;
        const int z  = (int)(zo / (u32)c_out);
        const int o  = (int)(zo % (u32)c_out);
        const int jt = j >> 4, jl = j & 15;

        const float* W   = (z == 0) ? W0  : ((z == 1) ? W1  : W2);
        const float* cb  = (z == 0) ? cb0 : ((z == 1) ? cb1 : cb2);
        const float* bnp = (z == 0) ? bn0 : ((z == 1) ? bn1 : bn2);
        const float* lw  = (z == 0) ? lw0 : ((z == 1) ? lw1 : lw2);
        u8* SOUT         = (z == 0) ? S0  : ((z == 1) ? S1  : S2);

        double acc[4] = {0.0, 0.0, 0.0, 0.0};
        for (int c = lane; c < c_in; c += 64) {
            const double w = (double)W[(size_t)o * c_in + c];
#pragma unroll
            for (int t = 0; t < 4; ++t) {
                double xval;
                if (IN_MODE == 1) {
                    const int kb = c >> 5, part = (c & 31) >> 3, elem = c & 7;
                    const size_t idx = (((size_t)(jt * nkb + kb) * 4 + t) << 9)
                                     + (size_t)((jl + (part << 4)) << 3) + elem;
                    xval = (double)bfbits2f(XTs[idx]);
                } else {
                    const size_t i = ((size_t)(t * NCOL + j)) * c_in + c;
                    if (IN_MODE == 0) xval = (double)XTf[i];
                    else              xval = (double)XTf[i] + (double)SPT[i];
                }
                acc[t] = fma(w, xval, acc[t]);
            }
        }
#pragma unroll
        for (int m = 32; m; m >>= 1) {
#pragma unroll
            for (int t = 0; t < 4; ++t)
                acc[t] += __shfl_xor(acc[t], m, 64);
        }

        if (lane == 0) {
            const double tau = 1.0 / (1.0 + exp(-(double)lw[0]));
            const double g  = (double)bnp[o];
            const double be = (double)bnp[c_out + o];
            const double mm = (double)bnp[2 * c_out + o];
            const double vv = (double)bnp[3 * c_out + o];
            const double inv   = g / sqrt(vv + 1e-5);
            const double shift = be - mm * inv;
            const double cbv   = cb ? (double)cb[o] : 0.0;
            const size_t per_t = (size_t)B_ * c_out * N_;
            const int jb = j / N_, jn = j % N_;
            const size_t idx0  = ((size_t)jb * c_out + o) * N_ + jn;
            double v = 0.0;
#pragma unroll
            for (int t = 0; t < 4; ++t) {
                const double yv = (acc[t] + cbv) * inv + shift;
                const double h  = v + (yv - v) * tau;
                const double sp = (h >= 1.0) ? 1.0 : 0.0;
                v = h * (1.0 - sp);
                const size_t idx = (size_t)t * per_t + idx0;
                if (OM == 0) SOUT[idx] = (u8)sp;
                else out[idx] = (float)((double)xres[idx] + (double)sres[idx] + sp);
            }
        }
    }
}

// ---------------------------------------------------------------------------
// Spike attention + fused LIF (exact dyadic arithmetic, r5-r16 proven math).
// n-split NS=2 (r16): each block recomputes kv (exact) and handles a
// 98-column slice.  Bit-identical outputs.
// ---------------------------------------------------------------------------
__global__ __launch_bounds__(256) void attn_lif_kernel(
    const u8* __restrict__ SQ, const u8* __restrict__ SK, const u8* __restrict__ SV,
    u8* __restrict__ SATT, const float* __restrict__ lw)
{
    __shared__ u8 q_lds[DH_ * NSLC];      // 3136 B (slice only)
    __shared__ u8 k_lds[DH_ * N_];        // 6272 B (full)
    __shared__ u8 v_lds[DH_ * N_];
    __shared__ float kv_lds[DH_ * DH_];   // 4 KB
    __shared__ float vstate[DH_ * NSLC];  // 12.5 KB (slice only)
    const int tid = threadIdx.x;
    const int slc = blockIdx.x & 1;
    const int bh  = blockIdx.x >> 1;
    const int b = bh / NH_, h = bh % NH_;
    const int n0 = slc * NSLC;
    const float tau = 1.0f / (1.0f + expf(-lw[0]));

    for (int i = tid; i < DH_ * NSLC; i += 256) vstate[i] = 0.0f;

    for (int t = 0; t < T_; ++t) {
        const size_t base = ((size_t)((t * B_ + b) * C_) + h * DH_) * N_;
        __syncthreads();
        for (int i = tid; i < DH_ * N_ / 4; i += 256) {
            ((unsigned int*)k_lds)[i] = ((const unsigned int*)(SK + base))[i];
            ((unsigned int*)v_lds)[i] = ((const unsigned int*)(SV + base))[i];
        }
        for (int i = tid; i < DH_ * NSLC; i += 256) {
            const int row = i / NSLC, col = i % NSLC;
            q_lds[i] = SQ[base + (size_t)row * N_ + n0 + col];
        }
        __syncthreads();

#pragma unroll
        for (int r = 0; r < 4; ++r) {
            const int e = tid + 256 * r;
            const int i = e >> 5, jj = e & 31;
            int s = 0;
            for (int nn = 0; nn < N_; nn += 4) {
                uchar4 kk = *(const uchar4*)&k_lds[i * N_ + nn];
                uchar4 uv = *(const uchar4*)&v_lds[jj * N_ + nn];
                s += kk.x * uv.x + kk.y * uv.y + kk.z * uv.z + kk.w * uv.w;
            }
            kv_lds[e] = (float)s;
        }
        __syncthreads();

        for (int e = tid; e < DH_ * NSLC; e += 256) {
            const int jj = e / NSLC, nn = e % NSLC;
            float s = 0.0f;
#pragma unroll
            for (int i = 0; i < DH_; ++i)
                s += q_lds[i * NSLC + nn] ? kv_lds[i * DH_ + jj] : 0.0f;
            const float att = 0.125f * s;
            const float v = vstate[e];
            const float hh = v + (att - v) * tau;
            const float sp = (hh >= 1.0f) ? 1.0f : 0.0f;
            vstate[e] = hh * (1.0f - sp);
            SATT[base + (size_t)jj * N_ + n0 + nn] = (u8)sp;
        }
    }
}

// ---------------------------------------------------------------------------
extern "C" void kernel_launch(void* const* d_in, const int* in_sizes, int n_in,
                              void* d_out, int out_size, void* d_ws, size_t ws_size,
                              hipStream_t stream)
{
    const float* x       = (const float*)d_in[0];
    const float* q_w     = (const float*)d_in[1];
    const float* q_bn    = (const float*)d_in[2];
    const float* q_lw    = (const float*)d_in[3];
    const float* k_w     = (const float*)d_in[4];
    const float* k_bn    = (const float*)d_in[5];
    const float* k_lw    = (const float*)d_in[6];
    const float* v_w     = (const float*)d_in[7];
    const float* v_bn    = (const float*)d_in[8];
    const float* v_lw    = (const float*)d_in[9];
    const float* attn_lw = (const float*)d_in[10];
    const float* proj_w  = (const float*)d_in[11];
    const float* proj_b  = (const float*)d_in[12];
    const float* proj_bn = (const float*)d_in[13];
    const float* proj_lw = (const float*)d_in[14];
    const float* fc1_w   = (const float*)d_in[15];
    const float* fc1_b   = (const float*)d_in[16];
    const float* fc1_bn  = (const float*)d_in[17];
    const float* fc1_lw  = (const float*)d_in[18];
    const float* fc2_w   = (const float*)d_in[19];
    const float* fc2_b   = (const float*)d_in[20];
    const float* fc2_bn  = (const float*)d_in[21];
    const float* fc2_lw  = (const float*)d_in[22];

    // ---- workspace layout (~154 MB), phase-aliased (r12-r16 proven) ----
    u8* base = (u8*)d_ws;
    float* XTf32   = (float*)(base);                // [0, 38.5M)   ph1-4 (exact x, linear-T)
    short* XTfr    = (short*)(base + 38535168);     // [38.5, 77.1) ph1 & ph4 (frag, hi+lo merged)
    short* SZfrag  = (short*)(base);                // [0, 77.1)    ph5 overlay (frag, c=1536, spikes)
    u8*    SQ      = base + 77070336;               // 9,633,792 each, ph1-2
    u8*    SK      = base + 86704128;
    u8*    SV      = base + 96337920;
    u8*    SATT    = base + 105971712;              // ph2-3
    u8*    SZ      = base + 77070336;               // ph4-5 overlay of SQ..SATT (u8 row-major)
    short* SATTfr  = (short*)(base + 115605504);    // 19.3M, ph3 (frag, spikes)
    u8*    SPT     = base + 115605504;              // 9.6M,  ph4 overlay (linear-T u8)
    u8*    SP      = base + 134873088;              // 9.6M,  ph3-5
    u32*   cnt     = (u32*)(base + 144506880);      // 256 B
    u32*   flags   = (u32*)(base + 144507136);      // 2.1M
    short* WAb     = (short*)(base + 146604288);    // 7.08M (frag, hi+lo merged)
    float* out = (float*)d_out;

    short *WAq = WAb,           *WAk = WAb + 294912, *WAv = WAb + 589824,
          *WAp = WAb + 884736,  *WA1 = WAb + 1179648, *WA2 = WAb + 2359296;
    u32 *flQ = flags, *flP = flags + FCAP, *fl1 = flags + 2 * FCAP, *fl2 = flags + 3 * FCAP;

    zero_counters<<<1, 64, 0, stream>>>(cnt);

    // 0. weight splits -> fragment layout (hi/lo adjacent)
    wprep<<<72, 256, 0, stream>>>(q_w,    WAq, C_, C_);
    wprep<<<72, 256, 0, stream>>>(k_w,    WAk, C_, C_);
    wprep<<<72, 256, 0, stream>>>(v_w,    WAv, C_, C_);
    wprep<<<72, 256, 0, stream>>>(proj_w, WAp, C_, C_);
    wprep<<<288, 256, 0, stream>>>(fc1_w, WA1, HID_, C_);
    wprep<<<288, 256, 0, stream>>>(fc2_w, WA2, C_, HID_);

    // 1. x -> frag superchunks + exact linear XTf32; fused q/k/v GEMM+LIF (OB2=2)
    tpose<0><<<128 * 6, 256, 0, stream>>>(x, nullptr, XTfr, XTf32, nullptr, C_, 6);
    gemm_lif<2, 0, 3, 2><<<98 * 3 * 3, 256, 0, stream>>>(
        XTfr, WAq, WAk, WAv,
        nullptr, nullptr, nullptr, q_bn, k_bn, v_bn, q_lw, k_lw, v_lw,
        SQ, SK, SV, nullptr, nullptr, nullptr, cnt + 0, flQ, C_, C_, 3);
    fixup_t<0, 0><<<512, 256, 0, stream>>>(
        XTf32, nullptr, q_w, k_w, v_w, nullptr, nullptr, nullptr,
        q_bn, k_bn, v_bn, q_lw, k_lw, v_lw,
        SQ, SK, SV, nullptr, nullptr, nullptr, cnt + 0, flQ, C_, C_);

    // 2. attention + LIF (exact), n-split x2
    attn_lif_kernel<<<B_ * NH_ * 2, 256, 0, stream>>>(SQ, SK, SV, SATT, attn_lw);

    // 3. proj: SATT -> frag (exact bf16); GEMM (OB2=1); fixup reads frag
    tpose<1><<<128 * 6, 256, 0, stream>>>(SATT, nullptr, SATTfr, nullptr, nullptr, C_, 6);
    gemm_lif<1, 0, 1, 1><<<98 * 6, 256, 0, stream>>>(
        SATTfr, WAp, WAp, WAp,
        proj_b, proj_b, proj_b, proj_bn, proj_bn, proj_bn, proj_lw, proj_lw, proj_lw,
        SP, SP, SP, nullptr, nullptr, nullptr, cnt + 1, flP, C_, C_, 6);
    fixup_t<1, 0><<<512, 256, 0, stream>>>(
        SATTfr, nullptr, proj_w, proj_w, proj_w, proj_b, proj_b, proj_b,
        proj_bn, proj_bn, proj_bn, proj_lw, proj_lw, proj_lw,
        SP, SP, SP, nullptr, nullptr, nullptr, cnt + 1, flP, C_, C_);

    // 4. fc1: (x+SP) -> frag superchunks + SPT; GEMM (OB2=2); fixup
    tpose<0><<<128 * 6, 256, 0, stream>>>(x, SP, XTfr, nullptr, SPT, C_, 6);
    gemm_lif<2, 0, 1, 2><<<98 * 12, 256, 0, stream>>>(
        XTfr, WA1, WA1, WA1,
        fc1_b, fc1_b, fc1_b, fc1_bn, fc1_bn, fc1_bn, fc1_lw, fc1_lw, fc1_lw,
        SZ, SZ, SZ, nullptr, nullptr, nullptr, cnt + 2, fl1, HID_, C_, 12);
    fixup_t<2, 0><<<512, 256, 0, stream>>>(
        XTf32, SPT, fc1_w, fc1_w, fc1_w, fc1_b, fc1_b, fc1_b,
        fc1_bn, fc1_bn, fc1_bn, fc1_lw, fc1_lw, fc1_lw,
        SZ, SZ, SZ, nullptr, nullptr, nullptr, cnt + 2, fl1, HID_, C_);

    // 5. fc2: SZ -> frag (exact bf16, overlays region A); GEMM (OB2=1) -> out
    tpose<1><<<128 * 24, 256, 0, stream>>>(SZ, nullptr, SZfrag, nullptr, nullptr, HID_, 24);
    gemm_lif<1, 1, 1, 1><<<98 * 6, 256, 0, stream>>>(
        SZfrag, WA2, WA2, WA2,
        fc2_b, fc2_b, fc2_b, fc2_bn, fc2_bn, fc2_bn, fc2_lw, fc2_lw, fc2_lw,
        nullptr, nullptr, nullptr, x, SP, out, cnt + 3, fl2, C_, HID_, 6);
    fixup_t<1, 1><<<512, 256, 0, stream>>>(
        SZfrag, nullptr, fc2_w, fc2_w, fc2_w, fc2_b, fc2_b, fc2_b,
        fc2_bn, fc2_bn, fc2_bn, fc2_lw, fc2_lw, fc2_lw,
        nullptr, nullptr, nullptr, x, SP, out, cnt + 3, fl2, C_, HID_);
}

// Round 18
// 901.258 us; speedup vs baseline: 1.0342x; 1.0342x over previous
//
#include <hip/hip_runtime.h>
#include <math.h>

#define T_   4
#define B_   32
#define C_   384
#define N_   196
#define HID_ 1536
#define NH_  12
#define DH_  32
#define NCOL (B_*N_)            // 6272 columns j=(b,n)
#define NJT  (NCOL/16)          // 392 j-tiles of 16
#define NSLC 98                 // attn n-slice (N_/2)
#define THRESH 2e-3f            // certainty margin (worst-case MFMA-path err ~3e-4)
#define FCAP (1u<<17)

typedef unsigned char u8;
typedef unsigned int  u32;
using bf16x8 = __attribute__((ext_vector_type(8))) short;
using f32x4  = __attribute__((ext_vector_type(4))) float;

__device__ __forceinline__ float bfbits2f(short u) {
    union { u32 i; float f; } c; c.i = ((u32)(unsigned short)u) << 16; return c.f;
}
__device__ __forceinline__ short f2bf(float f) {       // RNE f32 -> bf16 bits
    u32 b = __float_as_uint(f);
    return (short)((b + 0x7FFFu + ((b >> 16) & 1u)) >> 16);
}

__device__ __forceinline__ void gload_lds16(const short* g, short* l) {
    __builtin_amdgcn_global_load_lds(
        (const __attribute__((address_space(1))) void*)g,
        (__attribute__((address_space(3))) void*)l, 16, 0, 0);
}

__global__ void zero_counters(u32* cnt) { if (threadIdx.x < 4) cnt[threadIdx.x] = 0; }

// ---------------------------------------------------------------------------
// Weight split -> fragment-major, hi/lo ADJACENT (r14-proven):
// A[((ot*nkb + kb)*2 + s)*512 + (ol + 16*part)*8 + elem]
// ---------------------------------------------------------------------------
__global__ void wprep(const float* __restrict__ W, short* __restrict__ HL,
                      int c_out, int c_in)
{
    const int ng = c_out * (c_in >> 3);
    int i = blockIdx.x * 256 + threadIdx.x;
    if (i >= ng) return;
    const int o = i / (c_in >> 3);
    const int c = (i % (c_in >> 3)) << 3;
    const int ot = o >> 4, ol = o & 15;
    const int kb = c >> 5, part = (c & 31) >> 3;
    const int nkb = c_in >> 5;
    const size_t fp = (((size_t)(ot * nkb + kb) * 2) << 9) + (size_t)((ol + (part << 4)) << 3);
    short h8[8], l8[8];
#pragma unroll
    for (int k = 0; k < 8; ++k) {
        float f = W[(size_t)o * c_in + c + k];
        short h = f2bf(f);
        h8[k] = h;
        l8[k] = f2bf(f - bfbits2f(h));
    }
    *(bf16x8*)&HL[fp]       = *(bf16x8*)h8;
    *(bf16x8*)&HL[fp + 512] = *(bf16x8*)l8;
}

// ---------------------------------------------------------------------------
// Transpose [tb][c][n] -> fragment-major B superchunks (r14-proven):
//   SPL=2: B[((jt*nkb+kb)*8 + t*2 + s)*512 + (jl+16*part)*8 + elem]
//   SPL=1: B[((jt*nkb+kb)*4 + t    )*512 + ...]  (spikes, hi only, exact)
// + optional exact linear copies for the f64 fixups.
// ---------------------------------------------------------------------------
template<int MODE>
__global__ __launch_bounds__(256) void tpose(
    const void* __restrict__ src, const u8* __restrict__ Sadd,
    short* __restrict__ HL,
    float* __restrict__ F, u8* __restrict__ SPTo,
    int c_tot, int nct)
{
    __shared__ float lds[64][197];
    __shared__ u8 slds[MODE == 0 ? 64 : 1][MODE == 0 ? 197 : 1];
    const int tid = threadIdx.x;
    const int tb = blockIdx.x / nct;
    const int ct = blockIdx.x % nct;
    const int t = tb / B_, b = tb % B_;
    const int nkb = c_tot >> 5;
    const float* Xf = (const float*)src;
    const u8*    Xb = (const u8*)src;

    for (int i = tid; i < 64 * N_; i += 256) {
        int c = i / N_, n = i % N_;
        size_t g = ((size_t)tb * c_tot + ct * 64 + c) * N_ + n;
        if (MODE == 0) {
            float v = Xf[g];
            u8 s = Sadd ? Sadd[g] : (u8)0;
            lds[c][n] = v + (float)s;
            slds[c][n] = s;
        } else {
            lds[c][n] = (float)Xb[g];
        }
    }
    __syncthreads();

    for (int i = tid; i < N_ * 8; i += 256) {
        const int n = i >> 3;
        const int c_loc = (i & 7) << 3;
        const int c = ct * 64 + c_loc;
        const int j = b * N_ + n;
        const int jt = j >> 4, jl = j & 15;
        const int kb = c >> 5, part = (c & 31) >> 3;
        const size_t pos = (size_t)((jl + (part << 4)) << 3);
        short h8[8], l8[8];
        float f8[8];
#pragma unroll
        for (int k = 0; k < 8; ++k) {
            float f = lds[c_loc + k][n];
            f8[k] = f;
            short h = f2bf(f);
            h8[k] = h;
            if (MODE == 0) l8[k] = f2bf(f - bfbits2f(h));
        }
        if (MODE == 0) {
            const size_t fp = (((size_t)(jt * nkb + kb) * 8 + t * 2) << 9) + pos;
            *(bf16x8*)&HL[fp]       = *(bf16x8*)h8;
            *(bf16x8*)&HL[fp + 512] = *(bf16x8*)l8;
            if (F) {
                const size_t lp = ((size_t)(t * NCOL + j)) * c_tot + c;
                *(float4*)&F[lp]     = *(float4*)&f8[0];
                *(float4*)&F[lp + 4] = *(float4*)&f8[4];
            }
            if (SPTo) {
                const size_t lp = ((size_t)(t * NCOL + j)) * c_tot + c;
#pragma unroll
                for (int k = 0; k < 8; ++k) SPTo[lp + k] = slds[c_loc + k][n];
            }
        } else {
            const size_t fp = (((size_t)(jt * nkb + kb) * 4 + t) << 9) + pos;
            *(bf16x8*)&HL[fp] = *(bf16x8*)h8;
        }
    }
}

// ---------------------------------------------------------------------------
// MFMA GEMM + BN + LIF + flagging.  C[o,j,t] = sum_c W[o,c] X[t,j,c].
// r18: OCCUPANCY-FIRST.  OB=64o x 64j per block (acc = 64 AGPR), NO B
// ping/pong (saves 32 VGPR), minimal live state, __launch_bounds__(256,4)
// -> target total regs <=128 (unified VGPR+AGPR) = 16 waves/CU, double
// every prior round's latency-hiding.  A staged in 2x8KB LDS dbuf via
// global_load_lds (r13); B superchunk register loads (r14); XCD swizzle
// (r10).  MFMA accumulation order unchanged -> bit-identical results.
// D: col = lane&15, row = (lane>>4)*4 + reg  [m89-verified].
// ---------------------------------------------------------------------------
template<int SPLITS, int OM, int NZ>
__global__ __launch_bounds__(256, 4) void gemm_lif(
    const short* __restrict__ BHL,
    const short* __restrict__ WA0, const short* __restrict__ WA1, const short* __restrict__ WA2,
    const float* __restrict__ cb0, const float* __restrict__ cb1, const float* __restrict__ cb2,
    const float* __restrict__ bn0, const float* __restrict__ bn1, const float* __restrict__ bn2,
    const float* __restrict__ lw0, const float* __restrict__ lw1, const float* __restrict__ lw2,
    u8* S0, u8* S1, u8* S2,
    const float* __restrict__ xres, const u8* __restrict__ sres, float* __restrict__ out,
    u32* __restrict__ cnt, u32* __restrict__ flags,
    int c_out, int c_in, int nob)
{
    __shared__ short a_lds[2][8][512];     // 16 KB: [buf][os*2 + split][1KB]
    const int tid = threadIdx.x;
    const int w = tid >> 6, l = tid & 63;

    // ---- bijective XCD-contiguity swizzle (8 XCDs, m204 formula) ----
    const u32 nwg = gridDim.x;
    const u32 q = nwg >> 3, r = nwg & 7;
    const u32 xcd = blockIdx.x & 7, off = blockIdx.x >> 3;
    const u32 id = (xcd < r ? xcd * (q + 1) : r * (q + 1) + (xcd - r) * q) + off;

    const int mt  = (int)(id / (u32)(nob * NZ));
    const int rem = (int)(id % (u32)(nob * NZ));
    const int z  = (NZ == 1) ? 0 : (rem % NZ);
    const int ob = (NZ == 1) ? rem : (rem / NZ);

    const short* WA  = (z == 0) ? WA0 : ((z == 1) ? WA1 : WA2);
    const float* cb  = (z == 0) ? cb0 : ((z == 1) ? cb1 : cb2);
    const float* bnp = (z == 0) ? bn0 : ((z == 1) ? bn1 : bn2);
    const float* lw  = (z == 0) ? lw0 : ((z == 1) ? lw1 : lw2);
    u8* SOUT         = (z == 0) ? S0  : ((z == 1) ? S1  : S2);

    const int nkb = c_in >> 5;
    const int jt = mt * 4 + w;
    const int j  = jt * 16 + (l & 15);
    const int ob64 = ob * 64;

    f32x4 acc[4][4];
#pragma unroll
    for (int t = 0; t < 4; ++t)
#pragma unroll
        for (int os = 0; os < 4; ++os)
            acc[t][os] = (f32x4){0.f, 0.f, 0.f, 0.f};

    // B superchunk base: per kb, 8 (or 4) consecutive 1KB chunks
    const short* bbase = BHL + (size_t)l * 8;

    // single B fragment set (no ping/pong -> minimal registers)
    bf16x8 bh[4], bl[4];

    auto LOADB = [&](int kb) {
        const short* p = bbase + (((size_t)jt * nkb + kb) << (SPLITS == 2 ? 12 : 11));
#pragma unroll
        for (int t = 0; t < 4; ++t) {
            if (SPLITS == 2) {
                bh[t] = *(const bf16x8*)(p + ((size_t)(t * 2)     << 9));
                bl[t] = *(const bf16x8*)(p + ((size_t)(t * 2 + 1) << 9));
            } else {
                bh[t] = *(const bf16x8*)(p + ((size_t)t << 9));
            }
        }
    };
    // wave w stages chunks {2w, 2w+1} of A(kb) into buf p (1KB each, lane*16)
    auto STAGE = [&](int kb, int p) {
#pragma unroll
        for (int cc = 0; cc < 2; ++cc) {
            const int ch = w * 2 + cc;
            const int os = ch >> 1, split = ch & 1;
            const short* src = WA
                + ((((size_t)(ob * 4 + os) * nkb + kb) * 2 + split) << 9) + (size_t)l * 8;
            gload_lds16(src, &a_lds[p][ch][(size_t)l * 8]);
        }
    };
    auto COMPUTE = [&](int p) {
#pragma unroll
        for (int os = 0; os < 4; ++os) {
            const bf16x8 ah = *(const bf16x8*)&a_lds[p][os * 2][(size_t)l * 8];
            const bf16x8 al = *(const bf16x8*)&a_lds[p][os * 2 + 1][(size_t)l * 8];
#pragma unroll
            for (int t = 0; t < 4; ++t) {
                acc[t][os] = __builtin_amdgcn_mfma_f32_16x16x32_bf16(ah, bh[t], acc[t][os], 0, 0, 0);
                acc[t][os] = __builtin_amdgcn_mfma_f32_16x16x32_bf16(al, bh[t], acc[t][os], 0, 0, 0);
                if (SPLITS == 2)   // lo x lo term dropped (r11)
                    acc[t][os] = __builtin_amdgcn_mfma_f32_16x16x32_bf16(ah, bl[t], acc[t][os], 0, 0, 0);
            }
        }
    };

    STAGE(0, 0);
    __syncthreads();                       // buf0 ready
    for (int kb = 0; kb < nkb; ++kb) {
        const int p = kb & 1;
        if (kb + 1 < nkb) STAGE(kb + 1, p ^ 1);
        LOADB(kb);
        COMPUTE(p);
        __syncthreads();                   // next buf ready; this buf free
    }

    const float tau = 1.0f / (1.0f + expf(-lw[0]));
    const size_t per_t = (size_t)B_ * c_out * N_;
    const int jb = j / N_, jn = j % N_;
#pragma unroll
    for (int os = 0; os < 4; ++os) {
#pragma unroll
        for (int r2 = 0; r2 < 4; ++r2) {
            const int o = ob64 + os * 16 + (l >> 4) * 4 + r2;
            const float g  = bnp[o];
            const float be = bnp[c_out + o];
            const float mm = bnp[2 * c_out + o];
            const float vv = bnp[3 * c_out + o];
            const float inv   = g / sqrtf(vv + 1e-5f);
            const float shift = be - mm * inv;
            const float cbv   = cb ? cb[o] : 0.0f;
            const size_t idx0 = ((size_t)jb * c_out + o) * N_ + jn;
            float v = 0.0f;
            bool flag = false;
#pragma unroll
            for (int t = 0; t < 4; ++t) {
                const float yv = (acc[t][os][r2] + cbv) * inv + shift;
                const float h  = v + (yv - v) * tau;
                const float sp = (h >= 1.0f) ? 1.0f : 0.0f;
                flag = flag || (fabsf(h - 1.0f) < THRESH);
                v = h * (1.0f - sp);
                const size_t idx = (size_t)t * per_t + idx0;
                if (OM == 0) SOUT[idx] = (u8)sp;
                else out[idx] = (float)((double)xres[idx] + (double)sres[idx] + (double)sp);
            }
            if (flag) {
                u32 p2 = atomicAdd(cnt, 1u);
                if (p2 < FCAP) flags[p2] = ((u32)(z * c_out + o)) * (u32)NCOL + (u32)j;
            }
        }
    }
}

// ---------------------------------------------------------------------------
// f64 fixup (decision math = r5/r7-proven all-f64 path).
// IN_MODE 0: linear f32 XT; 1: fragment-major bf16 spikes (r14 layout);
// 2: linear f32 XT + linear u8 SPT.
// ---------------------------------------------------------------------------
template<int IN_MODE, int OM>
__global__ __launch_bounds__(256) void fixup_t(
    const void* __restrict__ XT, const u8* __restrict__ SPT,
    const float* __restrict__ W0, const float* __restrict__ W1, const float* __restrict__ W2,
    const float* __restrict__ cb0, const float* __restrict__ cb1, const float* __restrict__ cb2,
    const float* __restrict__ bn0, const float* __restrict__ bn1, const float* __restrict__ bn2,
    const float* __restrict__ lw0, const float* __restrict__ lw1, const float* __restrict__ lw2,
    u8* S0, u8* S1, u8* S2,
    const float* __restrict__ xres, const u8* __restrict__ sres, float* out,
    const u32* __restrict__ cnt, const u32* __restrict__ flags,
    int c_out, int c_in)
{
    const int lane = threadIdx.x & 63;
    const int wid  = (blockIdx.x * 256 + threadIdx.x) >> 6;
    const int nw   = (gridDim.x * 256) >> 6;
    u32 nrec = *cnt;
    if (nrec > FCAP) nrec = FCAP;

    const float* XTf = (const float*)XT;
    const short* XTs = (const short*)XT;
    const int nkb = c_in >> 5;

    for (u32 r = wid; r < nrec; r += nw) {
        const u32 rec = flags[r];
        const int j  = (int)(rec % (u32)NCOL);
        const u32 zo = rec / (u32)NCOL;
        const int z  = (int)(zo / (u32)c_out);
        const int o  = (int)(zo % (u32)c_out);
        const int jt = j >> 4, jl = j & 15;

        const float* W   = (z == 0) ? W0  : ((z == 1) ? W1  : W2);
        const float* cb  = (z == 0) ? cb0 : ((z == 1) ? cb1 : cb2);
        const float* bnp = (z == 0) ? bn0 : ((z == 1) ? bn1 : bn2);
        const float* lw  = (z == 0) ? lw0 : ((z == 1) ? lw1 : lw2);
        u8* SOUT         = (z == 0) ? S0  : ((z == 1) ? S1  : S2);

        double acc[4] = {0.0, 0.0, 0.0, 0.0};
        for (int c = lane; c < c_in; c += 64) {
            const double w = (double)W[(size_t)o * c_in + c];
#pragma unroll
            for (int t = 0; t < 4; ++t) {
                double xval;
                if (IN_MODE == 1) {
                    const int kb = c >> 5, part = (c & 31) >> 3, elem = c & 7;
                    const size_t idx = (((size_t)(jt * nkb + kb) * 4 + t) << 9)
                                     + (size_t)((jl + (part << 4)) << 3) + elem;
                    xval = (double)bfbits2f(XTs[idx]);
                } else {
                    const size_t i = ((size_t)(t * NCOL + j)) * c_in + c;
                    if (IN_MODE == 0) xval = (double)XTf[i];
                    else              xval = (double)XTf[i] + (double)SPT[i];
                }
                acc[t] = fma(w, xval, acc[t]);
            }
        }
#pragma unroll
        for (int m = 32; m; m >>= 1) {
#pragma unroll
            for (int t = 0; t < 4; ++t)
                acc[t] += __shfl_xor(acc[t], m, 64);
        }

        if (lane == 0) {
            const double tau = 1.0 / (1.0 + exp(-(double)lw[0]));
            const double g  = (double)bnp[o];
            const double be = (double)bnp[c_out + o];
            const double mm = (double)bnp[2 * c_out + o];
            const double vv = (double)bnp[3 * c_out + o];
            const double inv   = g / sqrt(vv + 1e-5);
            const double shift = be - mm * inv;
            const double cbv   = cb ? (double)cb[o] : 0.0;
            const size_t per_t = (size_t)B_ * c_out * N_;
            const int jb = j / N_, jn = j % N_;
            const size_t idx0  = ((size_t)jb * c_out + o) * N_ + jn;
            double v = 0.0;
#pragma unroll
            for (int t = 0; t < 4; ++t) {
                const double yv = (acc[t] + cbv) * inv + shift;
                const double h  = v + (yv - v) * tau;
                const double sp = (h >= 1.0) ? 1.0 : 0.0;
                v = h * (1.0 - sp);
                const size_t idx = (size_t)t * per_t + idx0;
                if (OM == 0) SOUT[idx] = (u8)sp;
                else out[idx] = (float)((double)xres[idx] + (double)sres[idx] + sp);
            }
        }
    }
}

// ---------------------------------------------------------------------------
// Spike attention + fused LIF (exact dyadic arithmetic, r5-r17 proven math).
// n-split NS=2 (r16): each block recomputes kv (exact) and handles a
// 98-column slice.  Bit-identical outputs.
// ---------------------------------------------------------------------------
__global__ __launch_bounds__(256) void attn_lif_kernel(
    const u8* __restrict__ SQ, const u8* __restrict__ SK, const u8* __restrict__ SV,
    u8* __restrict__ SATT, const float* __restrict__ lw)
{
    __shared__ u8 q_lds[DH_ * NSLC];      // 3136 B (slice only)
    __shared__ u8 k_lds[DH_ * N_];        // 6272 B (full)
    __shared__ u8 v_lds[DH_ * N_];
    __shared__ float kv_lds[DH_ * DH_];   // 4 KB
    __shared__ float vstate[DH_ * NSLC];  // 12.5 KB (slice only)
    const int tid = threadIdx.x;
    const int slc = blockIdx.x & 1;
    const int bh  = blockIdx.x >> 1;
    const int b = bh / NH_, h = bh % NH_;
    const int n0 = slc * NSLC;
    const float tau = 1.0f / (1.0f + expf(-lw[0]));

    for (int i = tid; i < DH_ * NSLC; i += 256) vstate[i] = 0.0f;

    for (int t = 0; t < T_; ++t) {
        const size_t base = ((size_t)((t * B_ + b) * C_) + h * DH_) * N_;
        __syncthreads();
        for (int i = tid; i < DH_ * N_ / 4; i += 256) {
            ((unsigned int*)k_lds)[i] = ((const unsigned int*)(SK + base))[i];
            ((unsigned int*)v_lds)[i] = ((const unsigned int*)(SV + base))[i];
        }
        for (int i = tid; i < DH_ * NSLC; i += 256) {
            const int row = i / NSLC, col = i % NSLC;
            q_lds[i] = SQ[base + (size_t)row * N_ + n0 + col];
        }
        __syncthreads();

#pragma unroll
        for (int r = 0; r < 4; ++r) {
            const int e = tid + 256 * r;
            const int i = e >> 5, jj = e & 31;
            int s = 0;
            for (int nn = 0; nn < N_; nn += 4) {
                uchar4 kk = *(const uchar4*)&k_lds[i * N_ + nn];
                uchar4 uv = *(const uchar4*)&v_lds[jj * N_ + nn];
                s += kk.x * uv.x + kk.y * uv.y + kk.z * uv.z + kk.w * uv.w;
            }
            kv_lds[e] = (float)s;
        }
        __syncthreads();

        for (int e = tid; e < DH_ * NSLC; e += 256) {
            const int jj = e / NSLC, nn = e % NSLC;
            float s = 0.0f;
#pragma unroll
            for (int i = 0; i < DH_; ++i)
                s += q_lds[i * NSLC + nn] ? kv_lds[i * DH_ + jj] : 0.0f;
            const float att = 0.125f * s;
            const float v = vstate[e];
            const float hh = v + (att - v) * tau;
            const float sp = (hh >= 1.0f) ? 1.0f : 0.0f;
            vstate[e] = hh * (1.0f - sp);
            SATT[base + (size_t)jj * N_ + n0 + nn] = (u8)sp;
        }
    }
}

// ---------------------------------------------------------------------------
extern "C" void kernel_launch(void* const* d_in, const int* in_sizes, int n_in,
                              void* d_out, int out_size, void* d_ws, size_t ws_size,
                              hipStream_t stream)
{
    const float* x       = (const float*)d_in[0];
    const float* q_w     = (const float*)d_in[1];
    const float* q_bn    = (const float*)d_in[2];
    const float* q_lw    = (const float*)d_in[3];
    const float* k_w     = (const float*)d_in[4];
    const float* k_bn    = (const float*)d_in[5];
    const float* k_lw    = (const float*)d_in[6];
    const float* v_w     = (const float*)d_in[7];
    const float* v_bn    = (const float*)d_in[8];
    const float* v_lw    = (const float*)d_in[9];
    const float* attn_lw = (const float*)d_in[10];
    const float* proj_w  = (const float*)d_in[11];
    const float* proj_b  = (const float*)d_in[12];
    const float* proj_bn = (const float*)d_in[13];
    const float* proj_lw = (const float*)d_in[14];
    const float* fc1_w   = (const float*)d_in[15];
    const float* fc1_b   = (const float*)d_in[16];
    const float* fc1_bn  = (const float*)d_in[17];
    const float* fc1_lw  = (const float*)d_in[18];
    const float* fc2_w   = (const float*)d_in[19];
    const float* fc2_b   = (const float*)d_in[20];
    const float* fc2_bn  = (const float*)d_in[21];
    const float* fc2_lw  = (const float*)d_in[22];

    // ---- workspace layout (~154 MB), phase-aliased (r12-r17 proven) ----
    u8* base = (u8*)d_ws;
    float* XTf32   = (float*)(base);                // [0, 38.5M)   ph1-4 (exact x, linear-T)
    short* XTfr    = (short*)(base + 38535168);     // [38.5, 77.1) ph1 & ph4 (frag, hi+lo merged)
    short* SZfrag  = (short*)(base);                // [0, 77.1)    ph5 overlay (frag, c=1536, spikes)
    u8*    SQ      = base + 77070336;               // 9,633,792 each, ph1-2
    u8*    SK      = base + 86704128;
    u8*    SV      = base + 96337920;
    u8*    SATT    = base + 105971712;              // ph2-3
    u8*    SZ      = base + 77070336;               // ph4-5 overlay of SQ..SATT (u8 row-major)
    short* SATTfr  = (short*)(base + 115605504);    // 19.3M, ph3 (frag, spikes)
    u8*    SPT     = base + 115605504;              // 9.6M,  ph4 overlay (linear-T u8)
    u8*    SP      = base + 134873088;              // 9.6M,  ph3-5
    u32*   cnt     = (u32*)(base + 144506880);      // 256 B
    u32*   flags   = (u32*)(base + 144507136);      // 2.1M
    short* WAb     = (short*)(base + 146604288);    // 7.08M (frag, hi+lo merged)
    float* out = (float*)d_out;

    short *WAq = WAb,           *WAk = WAb + 294912, *WAv = WAb + 589824,
          *WAp = WAb + 884736,  *WA1 = WAb + 1179648, *WA2 = WAb + 2359296;
    u32 *flQ = flags, *flP = flags + FCAP, *fl1 = flags + 2 * FCAP, *fl2 = flags + 3 * FCAP;

    zero_counters<<<1, 64, 0, stream>>>(cnt);

    // 0. weight splits -> fragment layout (hi/lo adjacent)
    wprep<<<72, 256, 0, stream>>>(q_w,    WAq, C_, C_);
    wprep<<<72, 256, 0, stream>>>(k_w,    WAk, C_, C_);
    wprep<<<72, 256, 0, stream>>>(v_w,    WAv, C_, C_);
    wprep<<<72, 256, 0, stream>>>(proj_w, WAp, C_, C_);
    wprep<<<288, 256, 0, stream>>>(fc1_w, WA1, HID_, C_);
    wprep<<<288, 256, 0, stream>>>(fc2_w, WA2, C_, HID_);

    // 1. x -> frag superchunks + exact linear XTf32; fused q/k/v GEMM+LIF; fixup
    tpose<0><<<128 * 6, 256, 0, stream>>>(x, nullptr, XTfr, XTf32, nullptr, C_, 6);
    gemm_lif<2, 0, 3><<<98 * 6 * 3, 256, 0, stream>>>(
        XTfr, WAq, WAk, WAv,
        nullptr, nullptr, nullptr, q_bn, k_bn, v_bn, q_lw, k_lw, v_lw,
        SQ, SK, SV, nullptr, nullptr, nullptr, cnt + 0, flQ, C_, C_, 6);
    fixup_t<0, 0><<<512, 256, 0, stream>>>(
        XTf32, nullptr, q_w, k_w, v_w, nullptr, nullptr, nullptr,
        q_bn, k_bn, v_bn, q_lw, k_lw, v_lw,
        SQ, SK, SV, nullptr, nullptr, nullptr, cnt + 0, flQ, C_, C_);

    // 2. attention + LIF (exact), n-split x2
    attn_lif_kernel<<<B_ * NH_ * 2, 256, 0, stream>>>(SQ, SK, SV, SATT, attn_lw);

    // 3. proj: SATT -> frag (exact bf16); GEMM; fixup reads frag directly
    tpose<1><<<128 * 6, 256, 0, stream>>>(SATT, nullptr, SATTfr, nullptr, nullptr, C_, 6);
    gemm_lif<1, 0, 1><<<98 * 6, 256, 0, stream>>>(
        SATTfr, WAp, WAp, WAp,
        proj_b, proj_b, proj_b, proj_bn, proj_bn, proj_bn, proj_lw, proj_lw, proj_lw,
        SP, SP, SP, nullptr, nullptr, nullptr, cnt + 1, flP, C_, C_, 6);
    fixup_t<1, 0><<<512, 256, 0, stream>>>(
        SATTfr, nullptr, proj_w, proj_w, proj_w, proj_b, proj_b, proj_b,
        proj_bn, proj_bn, proj_bn, proj_lw, proj_lw, proj_lw,
        SP, SP, SP, nullptr, nullptr, nullptr, cnt + 1, flP, C_, C_);

    // 4. fc1: (x+SP) -> frag superchunks + SPT; GEMM; fixup reads XTf32 + SPT
    tpose<0><<<128 * 6, 256, 0, stream>>>(x, SP, XTfr, nullptr, SPT, C_, 6);
    gemm_lif<2, 0, 1><<<98 * 24, 256, 0, stream>>>(
        XTfr, WA1, WA1, WA1,
        fc1_b, fc1_b, fc1_b, fc1_bn, fc1_bn, fc1_bn, fc1_lw, fc1_lw, fc1_lw,
        SZ, SZ, SZ, nullptr, nullptr, nullptr, cnt + 2, fl1, HID_, C_, 24);
    fixup_t<2, 0><<<512, 256, 0, stream>>>(
        XTf32, SPT, fc1_w, fc1_w, fc1_w, fc1_b, fc1_b, fc1_b,
        fc1_bn, fc1_bn, fc1_bn, fc1_lw, fc1_lw, fc1_lw,
        SZ, SZ, SZ, nullptr, nullptr, nullptr, cnt + 2, fl1, HID_, C_);

    // 5. fc2: SZ -> frag (exact bf16, overlays region A); GEMM -> out; fixup
    tpose<1><<<128 * 24, 256, 0, stream>>>(SZ, nullptr, SZfrag, nullptr, nullptr, HID_, 24);
    gemm_lif<1, 1, 1><<<98 * 6, 256, 0, stream>>>(
        SZfrag, WA2, WA2, WA2,
        fc2_b, fc2_b, fc2_b, fc2_bn, fc2_bn, fc2_bn, fc2_lw, fc2_lw, fc2_lw,
        nullptr, nullptr, nullptr, x, SP, out, cnt + 3, fl2, C_, HID_, 6);
    fixup_t<1, 1><<<512, 256, 0, stream>>>(
        SZfrag, nullptr, fc2_w, fc2_w, fc2_w, fc2_b, fc2_b, fc2_b,
        fc2_bn, fc2_bn, fc2_bn, fc2_lw, fc2_lw, fc2_lw,
        nullptr, nullptr, nullptr, x, SP, out, cnt + 3, fl2, C_, HID_);
}

// Round 19
// 881.386 us; speedup vs baseline: 1.0575x; 1.0225x over previous
//
#include <hip/hip_runtime.h>
#include <math.h>

#define T_   4
#define B_   32
#define C_   384
#define N_   196
#define HID_ 1536
#define NH_  12
#define DH_  32
#define NCOL (B_*N_)            // 6272 columns j=(b,n)
#define NJT  (NCOL/16)          // 392 j-tiles of 16
#define NSLC 98                 // attn n-slice (N_/2)
#define THRESH 2e-3f            // certainty margin (worst-case MFMA-path err ~3e-4)
#define FCAP (1u<<17)

typedef unsigned char u8;
typedef unsigned int  u32;
typedef unsigned long long u64;
using bf16x8 = __attribute__((ext_vector_type(8))) short;
using f32x4  = __attribute__((ext_vector_type(4))) float;

__device__ __forceinline__ float bfbits2f(short u) {
    union { u32 i; float f; } c; c.i = ((u32)(unsigned short)u) << 16; return c.f;
}
__device__ __forceinline__ short f2bf(float f) {       // RNE f32 -> bf16 bits
    u32 b = __float_as_uint(f);
    return (short)((b + 0x7FFFu + ((b >> 16) & 1u)) >> 16);
}
// u8 spikes (0/1) -> exact bf16 bits (0x0000 / 0x3F80)
__device__ __forceinline__ bf16x8 u8x8_to_bf16(uint2 raw) {
    short s[8];
#pragma unroll
    for (int k = 0; k < 4; ++k) {
        s[k]     = ((raw.x >> (8 * k)) & 0xFFu) ? (short)0x3F80 : (short)0;
        s[k + 4] = ((raw.y >> (8 * k)) & 0xFFu) ? (short)0x3F80 : (short)0;
    }
    return *(bf16x8*)s;
}

__device__ __forceinline__ void gload_lds16(const short* g, short* l) {
    __builtin_amdgcn_global_load_lds(
        (const __attribute__((address_space(1))) void*)g,
        (__attribute__((address_space(3))) void*)l, 16, 0, 0);
}

__global__ void zero_counters(u32* cnt) { if (threadIdx.x < 4) cnt[threadIdx.x] = 0; }

// ---------------------------------------------------------------------------
// Weight split -> fragment-major, hi/lo ADJACENT (r14-proven):
// A[((ot*nkb + kb)*2 + s)*512 + (ol + 16*part)*8 + elem]
// ---------------------------------------------------------------------------
__global__ void wprep(const float* __restrict__ W, short* __restrict__ HL,
                      int c_out, int c_in)
{
    const int ng = c_out * (c_in >> 3);
    int i = blockIdx.x * 256 + threadIdx.x;
    if (i >= ng) return;
    const int o = i / (c_in >> 3);
    const int c = (i % (c_in >> 3)) << 3;
    const int ot = o >> 4, ol = o & 15;
    const int kb = c >> 5, part = (c & 31) >> 3;
    const int nkb = c_in >> 5;
    const size_t fp = (((size_t)(ot * nkb + kb) * 2) << 9) + (size_t)((ol + (part << 4)) << 3);
    short h8[8], l8[8];
#pragma unroll
    for (int k = 0; k < 8; ++k) {
        float f = W[(size_t)o * c_in + c + k];
        short h = f2bf(f);
        h8[k] = h;
        l8[k] = f2bf(f - bfbits2f(h));
    }
    *(bf16x8*)&HL[fp]       = *(bf16x8*)h8;
    *(bf16x8*)&HL[fp + 512] = *(bf16x8*)l8;
}

// ---------------------------------------------------------------------------
// Transpose [tb][c][n] -> fragment-major B superchunks.
// MODE 0 (f32 + optional u8 Sadd): bf16 hi/lo frags (r14 layout) + optional
//   exact linear f32 F and u8 SPT copies.
// MODE 1 (u8 spikes): U8 FRAGMENTS (r19): frag[((jt*nkb+kb)*4+t)*512 + pos]
//   = spike byte (consumers convert to bf16 in-register, bit-exact).
// ---------------------------------------------------------------------------
template<int MODE>
__global__ __launch_bounds__(256) void tpose(
    const void* __restrict__ src, const u8* __restrict__ Sadd,
    void* __restrict__ HLv,
    float* __restrict__ F, u8* __restrict__ SPTo,
    int c_tot, int nct)
{
    __shared__ float lds[64][197];
    __shared__ u8 slds[MODE == 0 ? 64 : 1][MODE == 0 ? 197 : 1];
    const int tid = threadIdx.x;
    const int tb = blockIdx.x / nct;
    const int ct = blockIdx.x % nct;
    const int t = tb / B_, b = tb % B_;
    const int nkb = c_tot >> 5;
    const float* Xf = (const float*)src;
    const u8*    Xb = (const u8*)src;
    short* HL  = (short*)HLv;
    u8*    HL8 = (u8*)HLv;

    for (int i = tid; i < 64 * N_; i += 256) {
        int c = i / N_, n = i % N_;
        size_t g = ((size_t)tb * c_tot + ct * 64 + c) * N_ + n;
        if (MODE == 0) {
            float v = Xf[g];
            u8 s = Sadd ? Sadd[g] : (u8)0;
            lds[c][n] = v + (float)s;
            slds[c][n] = s;
        } else {
            lds[c][n] = (float)Xb[g];
        }
    }
    __syncthreads();

    for (int i = tid; i < N_ * 8; i += 256) {
        const int n = i >> 3;
        const int c_loc = (i & 7) << 3;
        const int c = ct * 64 + c_loc;
        const int j = b * N_ + n;
        const int jt = j >> 4, jl = j & 15;
        const int kb = c >> 5, part = (c & 31) >> 3;
        const size_t pos = (size_t)((jl + (part << 4)) << 3);
        if (MODE == 0) {
            short h8[8], l8[8];
            float f8[8];
#pragma unroll
            for (int k = 0; k < 8; ++k) {
                float f = lds[c_loc + k][n];
                f8[k] = f;
                short h = f2bf(f);
                h8[k] = h;
                l8[k] = f2bf(f - bfbits2f(h));
            }
            const size_t fp = (((size_t)(jt * nkb + kb) * 8 + t * 2) << 9) + pos;
            *(bf16x8*)&HL[fp]       = *(bf16x8*)h8;
            *(bf16x8*)&HL[fp + 512] = *(bf16x8*)l8;
            if (F) {
                const size_t lp = ((size_t)(t * NCOL + j)) * c_tot + c;
                *(float4*)&F[lp]     = *(float4*)&f8[0];
                *(float4*)&F[lp + 4] = *(float4*)&f8[4];
            }
            if (SPTo) {
                const size_t lp = ((size_t)(t * NCOL + j)) * c_tot + c;
#pragma unroll
                for (int k = 0; k < 8; ++k) SPTo[lp + k] = slds[c_loc + k][n];
            }
        } else {
            u64 v = 0;
#pragma unroll
            for (int k = 0; k < 8; ++k)
                v |= (u64)(u8)lds[c_loc + k][n] << (8 * k);
            const size_t fp = (((size_t)(jt * nkb + kb) * 4 + t) << 9) + pos;
            *(u64*)&HL8[fp] = v;
        }
    }
}

// ---------------------------------------------------------------------------
// MFMA GEMM + BN + LIF + flagging.  C[o,j,t] = sum_c W[o,c] X[t,j,c].
// r18 occupancy-first structure (64 VGPR, no B ping/pong, lb(256,4)).
// r19: OT template (o-tile 64 or 32); SPLITS=1 B = u8 frags + in-reg convert;
// OM: 0 = row-major u8 spikes; 1 = final f32 (xres+sres+spike);
//     2 = u8-FRAG spikes (direct SZfrag write, replaces the SZ tpose).
// D: col = lane&15, row = (lane>>4)*4 + reg  [m89-verified].
// ---------------------------------------------------------------------------
template<int SPLITS, int OM, int NZ, int OT>
__global__ __launch_bounds__(256, 4) void gemm_lif(
    const void* __restrict__ BHL,
    const short* __restrict__ WA0, const short* __restrict__ WA1, const short* __restrict__ WA2,
    const float* __restrict__ cb0, const float* __restrict__ cb1, const float* __restrict__ cb2,
    const float* __restrict__ bn0, const float* __restrict__ bn1, const float* __restrict__ bn2,
    const float* __restrict__ lw0, const float* __restrict__ lw1, const float* __restrict__ lw2,
    u8* S0, u8* S1, u8* S2,
    const float* __restrict__ xres, const u8* __restrict__ sres, float* __restrict__ out,
    u32* __restrict__ cnt, u32* __restrict__ flags,
    int c_out, int c_in, int nob)
{
    constexpr int NOS = OT / 16;                 // o-subtiles per thread (4 or 2)
    __shared__ short a_lds[2][NOS * 2][512];     // 16 KB (OT=64) / 8 KB (OT=32)
    const int tid = threadIdx.x;
    const int w = tid >> 6, l = tid & 63;

    // ---- bijective XCD-contiguity swizzle (8 XCDs, m204 formula) ----
    const u32 nwg = gridDim.x;
    const u32 q = nwg >> 3, r = nwg & 7;
    const u32 xcd = blockIdx.x & 7, off = blockIdx.x >> 3;
    const u32 id = (xcd < r ? xcd * (q + 1) : r * (q + 1) + (xcd - r) * q) + off;

    const int mt  = (int)(id / (u32)(nob * NZ));
    const int rem = (int)(id % (u32)(nob * NZ));
    const int z  = (NZ == 1) ? 0 : (rem % NZ);
    const int ob = (NZ == 1) ? rem : (rem / NZ);

    const short* WA  = (z == 0) ? WA0 : ((z == 1) ? WA1 : WA2);
    const float* cb  = (z == 0) ? cb0 : ((z == 1) ? cb1 : cb2);
    const float* bnp = (z == 0) ? bn0 : ((z == 1) ? bn1 : bn2);
    const float* lw  = (z == 0) ? lw0 : ((z == 1) ? lw1 : lw2);
    u8* SOUT         = (z == 0) ? S0  : ((z == 1) ? S1  : S2);

    const int nkb = c_in >> 5;
    const int jt = mt * 4 + w;
    const int j  = jt * 16 + (l & 15);
    const int obBase = ob * OT;

    f32x4 acc[4][NOS];
#pragma unroll
    for (int t = 0; t < 4; ++t)
#pragma unroll
        for (int os = 0; os < NOS; ++os)
            acc[t][os] = (f32x4){0.f, 0.f, 0.f, 0.f};

    const short* bbase16 = (const short*)BHL + (size_t)l * 8;   // SPLITS=2
    const u8*    bbase8  = (const u8*)BHL + (size_t)l * 8;      // SPLITS=1

    bf16x8 bh[4], bl[4];

    auto LOADB = [&](int kb) {
#pragma unroll
        for (int t = 0; t < 4; ++t) {
            if (SPLITS == 2) {
                const short* p = bbase16 + (((size_t)jt * nkb + kb) << 12);
                bh[t] = *(const bf16x8*)(p + ((size_t)(t * 2)     << 9));
                bl[t] = *(const bf16x8*)(p + ((size_t)(t * 2 + 1) << 9));
            } else {
                const u8* p = bbase8 + (((size_t)jt * nkb + kb) << 11);
                bh[t] = u8x8_to_bf16(*(const uint2*)(p + ((size_t)t << 9)));
            }
        }
    };
    // stage A(kb): NOS*2 chunks of 1KB; wave w stages NOS/2 of them
    auto STAGE = [&](int kb, int p) {
#pragma unroll
        for (int cc = 0; cc < NOS / 2; ++cc) {
            const int ch = w * (NOS / 2) + cc;
            const int os = ch >> 1, split = ch & 1;
            const short* src = WA
                + ((((size_t)(ob * NOS + os) * nkb + kb) * 2 + split) << 9) + (size_t)l * 8;
            gload_lds16(src, &a_lds[p][ch][(size_t)l * 8]);
        }
    };
    auto COMPUTE = [&](int p) {
#pragma unroll
        for (int os = 0; os < NOS; ++os) {
            const bf16x8 ah = *(const bf16x8*)&a_lds[p][os * 2][(size_t)l * 8];
            const bf16x8 al = *(const bf16x8*)&a_lds[p][os * 2 + 1][(size_t)l * 8];
#pragma unroll
            for (int t = 0; t < 4; ++t) {
                acc[t][os] = __builtin_amdgcn_mfma_f32_16x16x32_bf16(ah, bh[t], acc[t][os], 0, 0, 0);
                acc[t][os] = __builtin_amdgcn_mfma_f32_16x16x32_bf16(al, bh[t], acc[t][os], 0, 0, 0);
                if (SPLITS == 2)   // lo x lo term dropped (r11)
                    acc[t][os] = __builtin_amdgcn_mfma_f32_16x16x32_bf16(ah, bl[t], acc[t][os], 0, 0, 0);
            }
        }
    };

    STAGE(0, 0);
    __syncthreads();                       // buf0 ready
    for (int kb = 0; kb < nkb; ++kb) {
        const int p = kb & 1;
        if (kb + 1 < nkb) STAGE(kb + 1, p ^ 1);
        LOADB(kb);
        COMPUTE(p);
        __syncthreads();                   // next buf ready; this buf free
    }

    const float tau = 1.0f / (1.0f + expf(-lw[0]));
    const size_t per_t = (size_t)B_ * c_out * N_;
    const int jb = j / N_, jn = j % N_;
    const int nkbo = c_out >> 5;           // for OM==2 frag writes
#pragma unroll
    for (int os = 0; os < NOS; ++os) {
#pragma unroll
        for (int r2 = 0; r2 < 4; ++r2) {
            const int o = obBase + os * 16 + (l >> 4) * 4 + r2;
            const float g  = bnp[o];
            const float be = bnp[c_out + o];
            const float mm = bnp[2 * c_out + o];
            const float vv = bnp[3 * c_out + o];
            const float inv   = g / sqrtf(vv + 1e-5f);
            const float shift = be - mm * inv;
            const float cbv   = cb ? cb[o] : 0.0f;
            const size_t idx0 = ((size_t)jb * c_out + o) * N_ + jn;
            float v = 0.0f;
            bool flag = false;
#pragma unroll
            for (int t = 0; t < 4; ++t) {
                const float yv = (acc[t][os][r2] + cbv) * inv + shift;
                const float h  = v + (yv - v) * tau;
                const float sp = (h >= 1.0f) ? 1.0f : 0.0f;
                flag = flag || (fabsf(h - 1.0f) < THRESH);
                v = h * (1.0f - sp);
                if (OM == 0) {
                    SOUT[(size_t)t * per_t + idx0] = (u8)sp;
                } else if (OM == 1) {
                    const size_t idx = (size_t)t * per_t + idx0;
                    out[idx] = (float)((double)xres[idx] + (double)sres[idx] + (double)sp);
                } else {       // OM==2: u8 frag spike (SPL=1 layout)
                    const size_t fa = (((size_t)(jt * nkbo + (o >> 5)) * 4 + t) << 9)
                                    + (size_t)(((l & 15) + (((o & 31) >> 3) << 4)) << 3)
                                    + (o & 7);
                    SOUT[fa] = (u8)sp;
                }
            }
            if (flag) {
                u32 p2 = atomicAdd(cnt, 1u);
                if (p2 < FCAP) flags[p2] = ((u32)(z * c_out + o)) * (u32)NCOL + (u32)j;
            }
        }
    }
}

// ---------------------------------------------------------------------------
// f64 fixup (decision math = r5/r7-proven all-f64 path).
// IN_MODE 0: linear f32 XT; 1: U8 frag spikes (r19 layout); 2: f32 XT + SPT.
// OM 0: row-major u8 spikes; 1: final f32; 2: u8-frag spikes.
// ---------------------------------------------------------------------------
template<int IN_MODE, int OM>
__global__ __launch_bounds__(256) void fixup_t(
    const void* __restrict__ XT, const u8* __restrict__ SPT,
    const float* __restrict__ W0, const float* __restrict__ W1, const float* __restrict__ W2,
    const float* __restrict__ cb0, const float* __restrict__ cb1, const float* __restrict__ cb2,
    const float* __restrict__ bn0, const float* __restrict__ bn1, const float* __restrict__ bn2,
    const float* __restrict__ lw0, const float* __restrict__ lw1, const float* __restrict__ lw2,
    u8* S0, u8* S1, u8* S2,
    const float* __restrict__ xres, const u8* __restrict__ sres, float* out,
    const u32* __restrict__ cnt, const u32* __restrict__ flags,
    int c_out, int c_in)
{
    const int lane = threadIdx.x & 63;
    const int wid  = (blockIdx.x * 256 + threadIdx.x) >> 6;
    const int nw   = (gridDim.x * 256) >> 6;
    u32 nrec = *cnt;
    if (nrec > FCAP) nrec = FCAP;

    const float* XTf = (const float*)XT;
    const u8*    XT8 = (const u8*)XT;
    const int nkb = c_in >> 5;
    const int nkbo = c_out >> 5;

    for (u32 r = wid; r < nrec; r += nw) {
        const u32 rec = flags[r];
        const int j  = (int)(rec % (u32)NCOL);
        const u32 zo = rec / (u32)NCOL;
        const int z  = (int)(zo / (u32)c_out);
        const int o  = (int)(zo % (u32)c_out);
        const int jt = j >> 4, jl = j & 15;

        const float* W   = (z == 0) ? W0  : ((z == 1) ? W1  : W2);
        const float* cb  = (z == 0) ? cb0 : ((z == 1) ? cb1 : cb2);
        const float* bnp = (z == 0) ? bn0 : ((z == 1) ? bn1 : bn2);
        const float* lw  = (z == 0) ? lw0 : ((z == 1) ? lw1 : lw2);
        u8* SOUT         = (z == 0) ? S0  : ((z == 1) ? S1  : S2);

        double acc[4] = {0.0, 0.0, 0.0, 0.0};
        for (int c = lane; c < c_in; c += 64) {
            const double w = (double)W[(size_t)o * c_in + c];
#pragma unroll
            for (int t = 0; t < 4; ++t) {
                double xval;
                if (IN_MODE == 1) {
                    const int kb = c >> 5, part = (c & 31) >> 3, elem = c & 7;
                    const size_t idx = (((size_t)(jt * nkb + kb) * 4 + t) << 9)
                                     + (size_t)((jl + (part << 4)) << 3) + elem;
                    xval = (double)XT8[idx];
                } else {
                    const size_t i = ((size_t)(t * NCOL + j)) * c_in + c;
                    if (IN_MODE == 0) xval = (double)XTf[i];
                    else              xval = (double)XTf[i] + (double)SPT[i];
                }
                acc[t] = fma(w, xval, acc[t]);
            }
        }
#pragma unroll
        for (int m = 32; m; m >>= 1) {
#pragma unroll
            for (int t = 0; t < 4; ++t)
                acc[t] += __shfl_xor(acc[t], m, 64);
        }

        if (lane == 0) {
            const double tau = 1.0 / (1.0 + exp(-(double)lw[0]));
            const double g  = (double)bnp[o];
            const double be = (double)bnp[c_out + o];
            const double mm = (double)bnp[2 * c_out + o];
            const double vv = (double)bnp[3 * c_out + o];
            const double inv   = g / sqrt(vv + 1e-5);
            const double shift = be - mm * inv;
            const double cbv   = cb ? (double)cb[o] : 0.0;
            const size_t per_t = (size_t)B_ * c_out * N_;
            const int jb = j / N_, jn = j % N_;
            const size_t idx0  = ((size_t)jb * c_out + o) * N_ + jn;
            double v = 0.0;
#pragma unroll
            for (int t = 0; t < 4; ++t) {
                const double yv = (acc[t] + cbv) * inv + shift;
                const double h  = v + (yv - v) * tau;
                const double sp = (h >= 1.0) ? 1.0 : 0.0;
                v = h * (1.0 - sp);
                if (OM == 0) {
                    SOUT[(size_t)t * per_t + idx0] = (u8)sp;
                } else if (OM == 1) {
                    const size_t idx = (size_t)t * per_t + idx0;
                    out[idx] = (float)((double)xres[idx] + (double)sres[idx] + sp);
                } else {       // OM==2: u8 frag spike
                    const size_t fa = (((size_t)(jt * nkbo + (o >> 5)) * 4 + t) << 9)
                                    + (size_t)((jl + (((o & 31) >> 3) << 4)) << 3)
                                    + (o & 7);
                    SOUT[fa] = (u8)sp;
                }
            }
        }
    }
}

// ---------------------------------------------------------------------------
// Spike attention + fused LIF (exact dyadic arithmetic, r5-r18 proven math).
// n-split NS=2 (r16).  Bit-identical outputs.
// ---------------------------------------------------------------------------
__global__ __launch_bounds__(256) void attn_lif_kernel(
    const u8* __restrict__ SQ, const u8* __restrict__ SK, const u8* __restrict__ SV,
    u8* __restrict__ SATT, const float* __restrict__ lw)
{
    __shared__ u8 q_lds[DH_ * NSLC];
    __shared__ u8 k_lds[DH_ * N_];
    __shared__ u8 v_lds[DH_ * N_];
    __shared__ float kv_lds[DH_ * DH_];
    __shared__ float vstate[DH_ * NSLC];
    const int tid = threadIdx.x;
    const int slc = blockIdx.x & 1;
    const int bh  = blockIdx.x >> 1;
    const int b = bh / NH_, h = bh % NH_;
    const int n0 = slc * NSLC;
    const float tau = 1.0f / (1.0f + expf(-lw[0]));

    for (int i = tid; i < DH_ * NSLC; i += 256) vstate[i] = 0.0f;

    for (int t = 0; t < T_; ++t) {
        const size_t base = ((size_t)((t * B_ + b) * C_) + h * DH_) * N_;
        __syncthreads();
        for (int i = tid; i < DH_ * N_ / 4; i += 256) {
            ((unsigned int*)k_lds)[i] = ((const unsigned int*)(SK + base))[i];
            ((unsigned int*)v_lds)[i] = ((const unsigned int*)(SV + base))[i];
        }
        for (int i = tid; i < DH_ * NSLC; i += 256) {
            const int row = i / NSLC, col = i % NSLC;
            q_lds[i] = SQ[base + (size_t)row * N_ + n0 + col];
        }
        __syncthreads();

#pragma unroll
        for (int r = 0; r < 4; ++r) {
            const int e = tid + 256 * r;
            const int i = e >> 5, jj = e & 31;
            int s = 0;
            for (int nn = 0; nn < N_; nn += 4) {
                uchar4 kk = *(const uchar4*)&k_lds[i * N_ + nn];
                uchar4 uv = *(const uchar4*)&v_lds[jj * N_ + nn];
                s += kk.x * uv.x + kk.y * uv.y + kk.z * uv.z + kk.w * uv.w;
            }
            kv_lds[e] = (float)s;
        }
        __syncthreads();

        for (int e = tid; e < DH_ * NSLC; e += 256) {
            const int jj = e / NSLC, nn = e % NSLC;
            float s = 0.0f;
#pragma unroll
            for (int i = 0; i < DH_; ++i)
                s += q_lds[i * NSLC + nn] ? kv_lds[i * DH_ + jj] : 0.0f;
            const float att = 0.125f * s;
            const float v = vstate[e];
            const float hh = v + (att - v) * tau;
            const float sp = (hh >= 1.0f) ? 1.0f : 0.0f;
            vstate[e] = hh * (1.0f - sp);
            SATT[base + (size_t)jj * N_ + n0 + nn] = (u8)sp;
        }
    }
}

// ---------------------------------------------------------------------------
extern "C" void kernel_launch(void* const* d_in, const int* in_sizes, int n_in,
                              void* d_out, int out_size, void* d_ws, size_t ws_size,
                              hipStream_t stream)
{
    const float* x       = (const float*)d_in[0];
    const float* q_w     = (const float*)d_in[1];
    const float* q_bn    = (const float*)d_in[2];
    const float* q_lw    = (const float*)d_in[3];
    const float* k_w     = (const float*)d_in[4];
    const float* k_bn    = (const float*)d_in[5];
    const float* k_lw    = (const float*)d_in[6];
    const float* v_w     = (const float*)d_in[7];
    const float* v_bn    = (const float*)d_in[8];
    const float* v_lw    = (const float*)d_in[9];
    const float* attn_lw = (const float*)d_in[10];
    const float* proj_w  = (const float*)d_in[11];
    const float* proj_b  = (const float*)d_in[12];
    const float* proj_bn = (const float*)d_in[13];
    const float* proj_lw = (const float*)d_in[14];
    const float* fc1_w   = (const float*)d_in[15];
    const float* fc1_b   = (const float*)d_in[16];
    const float* fc1_bn  = (const float*)d_in[17];
    const float* fc1_lw  = (const float*)d_in[18];
    const float* fc2_w   = (const float*)d_in[19];
    const float* fc2_b   = (const float*)d_in[20];
    const float* fc2_bn  = (const float*)d_in[21];
    const float* fc2_lw  = (const float*)d_in[22];

    // ---- workspace layout (~144 MB), phase-aliased (r19 re-plan) ----
    u8* base = (u8*)d_ws;
    float* XTf32   = (float*)(base);                // [0, 38.5M)      ph1..fc1fix
    short* XTfr    = (short*)(base + 38535168);     // [38.5, 77.07M)  ph1 & ph4 (bf16 hi/lo frags)
    u8*    SQ      = base + 77070336;               // ph1-2
    u8*    SK      = base + 86704128;
    u8*    SV      = base + 96337920;
    u8*    SATT    = base + 105971712;              // ph2-3, ends 115.6M
    u8*    SZfrag  = base + 77070336;               // ph4-5 overlay (38.5M u8 frags)
    u8*    SATTfr  = base + 115605504;              // 9.6M u8 frags, ph3
    u8*    SPT     = base + 115605504;              // 9.6M linear-T u8, ph4 overlay
    u8*    SP      = base + 125239296;              // 9.6M, ph3-5
    u32*   cnt     = (u32*)(base + 134873088);      // 256 B
    u32*   flags   = (u32*)(base + 134873344);      // 2.1M
    short* WAb     = (short*)(base + 136970496);    // 7.08M -> ends ~144.0M
    float* out = (float*)d_out;

    short *WAq = WAb,           *WAk = WAb + 294912, *WAv = WAb + 589824,
          *WAp = WAb + 884736,  *WA1 = WAb + 1179648, *WA2 = WAb + 2359296;
    u32 *flQ = flags, *flP = flags + FCAP, *fl1 = flags + 2 * FCAP, *fl2 = flags + 3 * FCAP;

    zero_counters<<<1, 64, 0, stream>>>(cnt);

    // 0. weight splits -> fragment layout (hi/lo adjacent)
    wprep<<<72, 256, 0, stream>>>(q_w,    WAq, C_, C_);
    wprep<<<72, 256, 0, stream>>>(k_w,    WAk, C_, C_);
    wprep<<<72, 256, 0, stream>>>(v_w,    WAv, C_, C_);
    wprep<<<72, 256, 0, stream>>>(proj_w, WAp, C_, C_);
    wprep<<<288, 256, 0, stream>>>(fc1_w, WA1, HID_, C_);
    wprep<<<288, 256, 0, stream>>>(fc2_w, WA2, C_, HID_);

    // 1. x -> frags + exact linear XTf32; fused q/k/v GEMM+LIF; fixup
    tpose<0><<<128 * 6, 256, 0, stream>>>(x, nullptr, XTfr, XTf32, nullptr, C_, 6);
    gemm_lif<2, 0, 3, 64><<<98 * 6 * 3, 256, 0, stream>>>(
        XTfr, WAq, WAk, WAv,
        nullptr, nullptr, nullptr, q_bn, k_bn, v_bn, q_lw, k_lw, v_lw,
        SQ, SK, SV, nullptr, nullptr, nullptr, cnt + 0, flQ, C_, C_, 6);
    fixup_t<0, 0><<<512, 256, 0, stream>>>(
        XTf32, nullptr, q_w, k_w, v_w, nullptr, nullptr, nullptr,
        q_bn, k_bn, v_bn, q_lw, k_lw, v_lw,
        SQ, SK, SV, nullptr, nullptr, nullptr, cnt + 0, flQ, C_, C_);

    // 2. attention + LIF (exact), n-split x2
    attn_lif_kernel<<<B_ * NH_ * 2, 256, 0, stream>>>(SQ, SK, SV, SATT, attn_lw);

    // 3. proj: SATT -> u8 frags; GEMM (u8-B); fixup reads u8 frags
    tpose<1><<<128 * 6, 256, 0, stream>>>(SATT, nullptr, SATTfr, nullptr, nullptr, C_, 6);
    gemm_lif<1, 0, 1, 64><<<98 * 6, 256, 0, stream>>>(
        SATTfr, WAp, WAp, WAp,
        proj_b, proj_b, proj_b, proj_bn, proj_bn, proj_bn, proj_lw, proj_lw, proj_lw,
        SP, SP, SP, nullptr, nullptr, nullptr, cnt + 1, flP, C_, C_, 6);
    fixup_t<1, 0><<<512, 256, 0, stream>>>(
        SATTfr, nullptr, proj_w, proj_w, proj_w, proj_b, proj_b, proj_b,
        proj_bn, proj_bn, proj_bn, proj_lw, proj_lw, proj_lw,
        SP, SP, SP, nullptr, nullptr, nullptr, cnt + 1, flP, C_, C_);

    // 4. fc1: (x+SP) -> frags + SPT; GEMM writes SZfrag u8 DIRECTLY (OM=2);
    //    fixup (f64, frag-out) corrects SZfrag
    tpose<0><<<128 * 6, 256, 0, stream>>>(x, SP, XTfr, nullptr, SPT, C_, 6);
    gemm_lif<2, 2, 1, 64><<<98 * 24, 256, 0, stream>>>(
        XTfr, WA1, WA1, WA1,
        fc1_b, fc1_b, fc1_b, fc1_bn, fc1_bn, fc1_bn, fc1_lw, fc1_lw, fc1_lw,
        SZfrag, SZfrag, SZfrag, nullptr, nullptr, nullptr, cnt + 2, fl1, HID_, C_, 24);
    fixup_t<2, 2><<<512, 256, 0, stream>>>(
        XTf32, SPT, fc1_w, fc1_w, fc1_w, fc1_b, fc1_b, fc1_b,
        fc1_bn, fc1_bn, fc1_bn, fc1_lw, fc1_lw, fc1_lw,
        SZfrag, SZfrag, SZfrag, nullptr, nullptr, nullptr, cnt + 2, fl1, HID_, C_);

    // 5. fc2 (OT=32, grid 1176): reads SZfrag u8; GEMM -> final f32 out; fixup
    gemm_lif<1, 1, 1, 32><<<98 * 12, 256, 0, stream>>>(
        SZfrag, WA2, WA2, WA2,
        fc2_b, fc2_b, fc2_b, fc2_bn, fc2_bn, fc2_bn, fc2_lw, fc2_lw, fc2_lw,
        nullptr, nullptr, nullptr, x, SP, out, cnt + 3, fl2, C_, HID_, 12);
    fixup_t<1, 1><<<512, 256, 0, stream>>>(
        SZfrag, nullptr, fc2_w, fc2_w, fc2_w, fc2_b, fc2_b, fc2_b,
        fc2_bn, fc2_bn, fc2_bn, fc2_lw, fc2_lw, fc2_lw,
        nullptr, nullptr, nullptr, x, SP, out, cnt + 3, fl2, C_, HID_);
}

// Round 20
// 845.538 us; speedup vs baseline: 1.1023x; 1.0424x over previous
//
#include <hip/hip_runtime.h>
#include <math.h>

#define T_   4
#define B_   32
#define C_   384
#define N_   196
#define HID_ 1536
#define NH_  12
#define DH_  32
#define NCOL (B_*N_)            // 6272 columns j=(b,n)
#define NJT  (NCOL/16)          // 392 j-tiles of 16
#define NSLC 49                 // attn n-slice (N_/4)
#define THRESH 2e-3f            // certainty margin (worst-case MFMA-path err ~3e-4)
#define FCAP (1u<<17)

typedef unsigned char u8;
typedef unsigned int  u32;
typedef unsigned long long u64;
using bf16x8 = __attribute__((ext_vector_type(8))) short;
using f32x4  = __attribute__((ext_vector_type(4))) float;

__device__ __forceinline__ float bfbits2f(short u) {
    union { u32 i; float f; } c; c.i = ((u32)(unsigned short)u) << 16; return c.f;
}
__device__ __forceinline__ short f2bf(float f) {       // RNE f32 -> bf16 bits
    u32 b = __float_as_uint(f);
    return (short)((b + 0x7FFFu + ((b >> 16) & 1u)) >> 16);
}
// u8 spikes (0/1) -> exact bf16 bits (0x0000 / 0x3F80)
__device__ __forceinline__ bf16x8 u8x8_to_bf16(uint2 raw) {
    short s[8];
#pragma unroll
    for (int k = 0; k < 4; ++k) {
        s[k]     = ((raw.x >> (8 * k)) & 0xFFu) ? (short)0x3F80 : (short)0;
        s[k + 4] = ((raw.y >> (8 * k)) & 0xFFu) ? (short)0x3F80 : (short)0;
    }
    return *(bf16x8*)s;
}

__device__ __forceinline__ void gload_lds16(const short* g, short* l) {
    __builtin_amdgcn_global_load_lds(
        (const __attribute__((address_space(1))) void*)g,
        (__attribute__((address_space(3))) void*)l, 16, 0, 0);
}

// ---------------------------------------------------------------------------
// r20: single prologue dispatch — all 6 weight splits (fragment-major,
// hi/lo adjacent, r14 layout) + counter zeroing, selected by blockIdx range.
// A[((ot*nkb + kb)*2 + s)*512 + (ol + 16*part)*8 + elem]
// ---------------------------------------------------------------------------
__global__ void wprep_all(
    const float* __restrict__ qw, const float* __restrict__ kw,
    const float* __restrict__ vw, const float* __restrict__ pw,
    const float* __restrict__ w1, const float* __restrict__ w2,
    short* __restrict__ WAq, short* __restrict__ WAk, short* __restrict__ WAv,
    short* __restrict__ WAp, short* __restrict__ WA1, short* __restrict__ WA2,
    u32* __restrict__ cnt)
{
    if (blockIdx.x == 0 && threadIdx.x < 4) cnt[threadIdx.x] = 0;
    const int b = blockIdx.x;
    const float* W; short* HL; int c_out, c_in, b0;
    if      (b < 72)  { W = qw; HL = WAq; c_out = C_;   c_in = C_;   b0 = 0;   }
    else if (b < 144) { W = kw; HL = WAk; c_out = C_;   c_in = C_;   b0 = 72;  }
    else if (b < 216) { W = vw; HL = WAv; c_out = C_;   c_in = C_;   b0 = 144; }
    else if (b < 288) { W = pw; HL = WAp; c_out = C_;   c_in = C_;   b0 = 216; }
    else if (b < 576) { W = w1; HL = WA1; c_out = HID_; c_in = C_;   b0 = 288; }
    else              { W = w2; HL = WA2; c_out = C_;   c_in = HID_; b0 = 576; }

    const int ng = c_out * (c_in >> 3);
    int i = (b - b0) * 256 + threadIdx.x;
    if (i >= ng) return;
    const int o = i / (c_in >> 3);
    const int c = (i % (c_in >> 3)) << 3;
    const int ot = o >> 4, ol = o & 15;
    const int kb = c >> 5, part = (c & 31) >> 3;
    const int nkb = c_in >> 5;
    const size_t fp = (((size_t)(ot * nkb + kb) * 2) << 9) + (size_t)((ol + (part << 4)) << 3);
    short h8[8], l8[8];
#pragma unroll
    for (int k = 0; k < 8; ++k) {
        float f = W[(size_t)o * c_in + c + k];
        short h = f2bf(f);
        h8[k] = h;
        l8[k] = f2bf(f - bfbits2f(h));
    }
    *(bf16x8*)&HL[fp]       = *(bf16x8*)h8;
    *(bf16x8*)&HL[fp + 512] = *(bf16x8*)l8;
}

// ---------------------------------------------------------------------------
// Transpose [tb][c][n] -> fragment-major B superchunks.
// MODE 0 (f32 + optional u8 Sadd): bf16 hi/lo frags (r14 layout) + optional
//   exact linear f32 F and u8 SPT copies.
// MODE 1 (u8 spikes): u8 fragments (r19): frag[((jt*nkb+kb)*4+t)*512 + pos].
// ---------------------------------------------------------------------------
template<int MODE>
__global__ __launch_bounds__(256) void tpose(
    const void* __restrict__ src, const u8* __restrict__ Sadd,
    void* __restrict__ HLv,
    float* __restrict__ F, u8* __restrict__ SPTo,
    int c_tot, int nct)
{
    __shared__ float lds[64][197];
    __shared__ u8 slds[MODE == 0 ? 64 : 1][MODE == 0 ? 197 : 1];
    const int tid = threadIdx.x;
    const int tb = blockIdx.x / nct;
    const int ct = blockIdx.x % nct;
    const int t = tb / B_, b = tb % B_;
    const int nkb = c_tot >> 5;
    const float* Xf = (const float*)src;
    const u8*    Xb = (const u8*)src;
    short* HL  = (short*)HLv;
    u8*    HL8 = (u8*)HLv;

    for (int i = tid; i < 64 * N_; i += 256) {
        int c = i / N_, n = i % N_;
        size_t g = ((size_t)tb * c_tot + ct * 64 + c) * N_ + n;
        if (MODE == 0) {
            float v = Xf[g];
            u8 s = Sadd ? Sadd[g] : (u8)0;
            lds[c][n] = v + (float)s;
            slds[c][n] = s;
        } else {
            lds[c][n] = (float)Xb[g];
        }
    }
    __syncthreads();

    for (int i = tid; i < N_ * 8; i += 256) {
        const int n = i >> 3;
        const int c_loc = (i & 7) << 3;
        const int c = ct * 64 + c_loc;
        const int j = b * N_ + n;
        const int jt = j >> 4, jl = j & 15;
        const int kb = c >> 5, part = (c & 31) >> 3;
        const size_t pos = (size_t)((jl + (part << 4)) << 3);
        if (MODE == 0) {
            short h8[8], l8[8];
            float f8[8];
#pragma unroll
            for (int k = 0; k < 8; ++k) {
                float f = lds[c_loc + k][n];
                f8[k] = f;
                short h = f2bf(f);
                h8[k] = h;
                l8[k] = f2bf(f - bfbits2f(h));
            }
            const size_t fp = (((size_t)(jt * nkb + kb) * 8 + t * 2) << 9) + pos;
            *(bf16x8*)&HL[fp]       = *(bf16x8*)h8;
            *(bf16x8*)&HL[fp + 512] = *(bf16x8*)l8;
            if (F) {
                const size_t lp = ((size_t)(t * NCOL + j)) * c_tot + c;
                *(float4*)&F[lp]     = *(float4*)&f8[0];
                *(float4*)&F[lp + 4] = *(float4*)&f8[4];
            }
            if (SPTo) {
                const size_t lp = ((size_t)(t * NCOL + j)) * c_tot + c;
#pragma unroll
                for (int k = 0; k < 8; ++k) SPTo[lp + k] = slds[c_loc + k][n];
            }
        } else {
            u64 v = 0;
#pragma unroll
            for (int k = 0; k < 8; ++k)
                v |= (u64)(u8)lds[c_loc + k][n] << (8 * k);
            const size_t fp = (((size_t)(jt * nkb + kb) * 4 + t) << 9) + pos;
            *(u64*)&HL8[fp] = v;
        }
    }
}

// ---------------------------------------------------------------------------
// MFMA GEMM + BN + LIF + flagging.  C[o,j,t] = sum_c W[o,c] X[t,j,c].
// r18 occupancy-first structure (64 VGPR acc, no B ping/pong, lb(256,4)).
// OT: o-tile 64 or 32.  SPLITS=1 B = u8 frags + in-reg convert.
// OM: 0 = row-major u8 spikes; 1 = final f32 (xres+sres+spike);
//     2 = u8-frag spikes (direct SZfrag write).
// D: col = lane&15, row = (lane>>4)*4 + reg  [m89-verified].
// ---------------------------------------------------------------------------
template<int SPLITS, int OM, int NZ, int OT>
__global__ __launch_bounds__(256, 4) void gemm_lif(
    const void* __restrict__ BHL,
    const short* __restrict__ WA0, const short* __restrict__ WA1, const short* __restrict__ WA2,
    const float* __restrict__ cb0, const float* __restrict__ cb1, const float* __restrict__ cb2,
    const float* __restrict__ bn0, const float* __restrict__ bn1, const float* __restrict__ bn2,
    const float* __restrict__ lw0, const float* __restrict__ lw1, const float* __restrict__ lw2,
    u8* S0, u8* S1, u8* S2,
    const float* __restrict__ xres, const u8* __restrict__ sres, float* __restrict__ out,
    u32* __restrict__ cnt, u32* __restrict__ flags,
    int c_out, int c_in, int nob)
{
    constexpr int NOS = OT / 16;                 // o-subtiles per thread (4 or 2)
    __shared__ short a_lds[2][NOS * 2][512];     // 16 KB (OT=64) / 8 KB (OT=32)
    const int tid = threadIdx.x;
    const int w = tid >> 6, l = tid & 63;

    // ---- bijective XCD-contiguity swizzle (8 XCDs, m204 formula) ----
    const u32 nwg = gridDim.x;
    const u32 q = nwg >> 3, r = nwg & 7;
    const u32 xcd = blockIdx.x & 7, off = blockIdx.x >> 3;
    const u32 id = (xcd < r ? xcd * (q + 1) : r * (q + 1) + (xcd - r) * q) + off;

    const int mt  = (int)(id / (u32)(nob * NZ));
    const int rem = (int)(id % (u32)(nob * NZ));
    const int z  = (NZ == 1) ? 0 : (rem % NZ);
    const int ob = (NZ == 1) ? rem : (rem / NZ);

    const short* WA  = (z == 0) ? WA0 : ((z == 1) ? WA1 : WA2);
    const float* cb  = (z == 0) ? cb0 : ((z == 1) ? cb1 : cb2);
    const float* bnp = (z == 0) ? bn0 : ((z == 1) ? bn1 : bn2);
    const float* lw  = (z == 0) ? lw0 : ((z == 1) ? lw1 : lw2);
    u8* SOUT         = (z == 0) ? S0  : ((z == 1) ? S1  : S2);

    const int nkb = c_in >> 5;
    const int jt = mt * 4 + w;
    const int j  = jt * 16 + (l & 15);
    const int obBase = ob * OT;

    f32x4 acc[4][NOS];
#pragma unroll
    for (int t = 0; t < 4; ++t)
#pragma unroll
        for (int os = 0; os < NOS; ++os)
            acc[t][os] = (f32x4){0.f, 0.f, 0.f, 0.f};

    const short* bbase16 = (const short*)BHL + (size_t)l * 8;   // SPLITS=2
    const u8*    bbase8  = (const u8*)BHL + (size_t)l * 8;      // SPLITS=1

    bf16x8 bh[4], bl[4];

    auto LOADB = [&](int kb) {
#pragma unroll
        for (int t = 0; t < 4; ++t) {
            if (SPLITS == 2) {
                const short* p = bbase16 + (((size_t)jt * nkb + kb) << 12);
                bh[t] = *(const bf16x8*)(p + ((size_t)(t * 2)     << 9));
                bl[t] = *(const bf16x8*)(p + ((size_t)(t * 2 + 1) << 9));
            } else {
                const u8* p = bbase8 + (((size_t)jt * nkb + kb) << 11);
                bh[t] = u8x8_to_bf16(*(const uint2*)(p + ((size_t)t << 9)));
            }
        }
    };
    // stage A(kb): NOS*2 chunks of 1KB; wave w stages NOS/2 of them
    auto STAGE = [&](int kb, int p) {
#pragma unroll
        for (int cc = 0; cc < NOS / 2; ++cc) {
            const int ch = w * (NOS / 2) + cc;
            const int os = ch >> 1, split = ch & 1;
            const short* src = WA
                + ((((size_t)(ob * NOS + os) * nkb + kb) * 2 + split) << 9) + (size_t)l * 8;
            gload_lds16(src, &a_lds[p][ch][(size_t)l * 8]);
        }
    };
    auto COMPUTE = [&](int p) {
#pragma unroll
        for (int os = 0; os < NOS; ++os) {
            const bf16x8 ah = *(const bf16x8*)&a_lds[p][os * 2][(size_t)l * 8];
            const bf16x8 al = *(const bf16x8*)&a_lds[p][os * 2 + 1][(size_t)l * 8];
#pragma unroll
            for (int t = 0; t < 4; ++t) {
                acc[t][os] = __builtin_amdgcn_mfma_f32_16x16x32_bf16(ah, bh[t], acc[t][os], 0, 0, 0);
                acc[t][os] = __builtin_amdgcn_mfma_f32_16x16x32_bf16(al, bh[t], acc[t][os], 0, 0, 0);
                if (SPLITS == 2)   // lo x lo term dropped (r11)
                    acc[t][os] = __builtin_amdgcn_mfma_f32_16x16x32_bf16(ah, bl[t], acc[t][os], 0, 0, 0);
            }
        }
    };

    STAGE(0, 0);
    __syncthreads();                       // buf0 ready
    for (int kb = 0; kb < nkb; ++kb) {
        const int p = kb & 1;
        if (kb + 1 < nkb) STAGE(kb + 1, p ^ 1);
        LOADB(kb);
        COMPUTE(p);
        __syncthreads();                   // next buf ready; this buf free
    }

    const float tau = 1.0f / (1.0f + expf(-lw[0]));
    const size_t per_t = (size_t)B_ * c_out * N_;
    const int jb = j / N_, jn = j % N_;
    const int nkbo = c_out >> 5;           // for OM==2 frag writes
#pragma unroll
    for (int os = 0; os < NOS; ++os) {
#pragma unroll
        for (int r2 = 0; r2 < 4; ++r2) {
            const int o = obBase + os * 16 + (l >> 4) * 4 + r2;
            const float g  = bnp[o];
            const float be = bnp[c_out + o];
            const float mm = bnp[2 * c_out + o];
            const float vv = bnp[3 * c_out + o];
            const float inv   = g / sqrtf(vv + 1e-5f);
            const float shift = be - mm * inv;
            const float cbv   = cb ? cb[o] : 0.0f;
            const size_t idx0 = ((size_t)jb * c_out + o) * N_ + jn;
            float v = 0.0f;
            bool flag = false;
#pragma unroll
            for (int t = 0; t < 4; ++t) {
                const float yv = (acc[t][os][r2] + cbv) * inv + shift;
                const float h  = v + (yv - v) * tau;
                const float sp = (h >= 1.0f) ? 1.0f : 0.0f;
                flag = flag || (fabsf(h - 1.0f) < THRESH);
                v = h * (1.0f - sp);
                if (OM == 0) {
                    SOUT[(size_t)t * per_t + idx0] = (u8)sp;
                } else if (OM == 1) {
                    const size_t idx = (size_t)t * per_t + idx0;
                    out[idx] = (float)((double)xres[idx] + (double)sres[idx] + (double)sp);
                } else {       // OM==2: u8 frag spike (SPL=1 layout)
                    const size_t fa = (((size_t)(jt * nkbo + (o >> 5)) * 4 + t) << 9)
                                    + (size_t)(((l & 15) + (((o & 31) >> 3) << 4)) << 3)
                                    + (o & 7);
                    SOUT[fa] = (u8)sp;
                }
            }
            if (flag) {
                u32 p2 = atomicAdd(cnt, 1u);
                if (p2 < FCAP) flags[p2] = ((u32)(z * c_out + o)) * (u32)NCOL + (u32)j;
            }
        }
    }
}

// ---------------------------------------------------------------------------
// f64 fixup (decision math = r5/r7-proven all-f64 path).
// IN_MODE 0: linear f32 XT; 1: u8 frag spikes (r19 layout); 2: f32 XT + SPT.
// OM 0: row-major u8 spikes; 1: final f32; 2: u8-frag spikes.
// ---------------------------------------------------------------------------
template<int IN_MODE, int OM>
__global__ __launch_bounds__(256) void fixup_t(
    const void* __restrict__ XT, const u8* __restrict__ SPT,
    const float* __restrict__ W0, const float* __restrict__ W1, const float* __restrict__ W2,
    const float* __restrict__ cb0, const float* __restrict__ cb1, const float* __restrict__ cb2,
    const float* __restrict__ bn0, const float* __restrict__ bn1, const float* __restrict__ bn2,
    const float* __restrict__ lw0, const float* __restrict__ lw1, const float* __restrict__ lw2,
    u8* S0, u8* S1, u8* S2,
    const float* __restrict__ xres, const u8* __restrict__ sres, float* out,
    const u32* __restrict__ cnt, const u32* __restrict__ flags,
    int c_out, int c_in)
{
    const int lane = threadIdx.x & 63;
    const int wid  = (blockIdx.x * 256 + threadIdx.x) >> 6;
    const int nw   = (gridDim.x * 256) >> 6;
    u32 nrec = *cnt;
    if (nrec > FCAP) nrec = FCAP;

    const float* XTf = (const float*)XT;
    const u8*    XT8 = (const u8*)XT;
    const int nkb = c_in >> 5;
    const int nkbo = c_out >> 5;

    for (u32 r = wid; r < nrec; r += nw) {
        const u32 rec = flags[r];
        const int j  = (int)(rec % (u32)NCOL);
        const u32 zo = rec / (u32)NCOL;
        const int z  = (int)(zo / (u32)c_out);
        const int o  = (int)(zo % (u32)c_out);
        const int jt = j >> 4, jl = j & 15;

        const float* W   = (z == 0) ? W0  : ((z == 1) ? W1  : W2);
        const float* cb  = (z == 0) ? cb0 : ((z == 1) ? cb1 : cb2);
        const float* bnp = (z == 0) ? bn0 : ((z == 1) ? bn1 : bn2);
        const float* lw  = (z == 0) ? lw0 : ((z == 1) ? lw1 : lw2);
        u8* SOUT         = (z == 0) ? S0  : ((z == 1) ? S1  : S2);

        double acc[4] = {0.0, 0.0, 0.0, 0.0};
        for (int c = lane; c < c_in; c += 64) {
            const double w = (double)W[(size_t)o * c_in + c];
#pragma unroll
            for (int t = 0; t < 4; ++t) {
                double xval;
                if (IN_MODE == 1) {
                    const int kb = c >> 5, part = (c & 31) >> 3, elem = c & 7;
                    const size_t idx = (((size_t)(jt * nkb + kb) * 4 + t) << 9)
                                     + (size_t)((jl + (part << 4)) << 3) + elem;
                    xval = (double)XT8[idx];
                } else {
                    const size_t i = ((size_t)(t * NCOL + j)) * c_in + c;
                    if (IN_MODE == 0) xval = (double)XTf[i];
                    else              xval = (double)XTf[i] + (double)SPT[i];
                }
                acc[t] = fma(w, xval, acc[t]);
            }
        }
#pragma unroll
        for (int m = 32; m; m >>= 1) {
#pragma unroll
            for (int t = 0; t < 4; ++t)
                acc[t] += __shfl_xor(acc[t], m, 64);
        }

        if (lane == 0) {
            const double tau = 1.0 / (1.0 + exp(-(double)lw[0]));
            const double g  = (double)bnp[o];
            const double be = (double)bnp[c_out + o];
            const double mm = (double)bnp[2 * c_out + o];
            const double vv = (double)bnp[3 * c_out + o];
            const double inv   = g / sqrt(vv + 1e-5);
            const double shift = be - mm * inv;
            const double cbv   = cb ? (double)cb[o] : 0.0;
            const size_t per_t = (size_t)B_ * c_out * N_;
            const int jb = j / N_, jn = j % N_;
            const size_t idx0  = ((size_t)jb * c_out + o) * N_ + jn;
            double v = 0.0;
#pragma unroll
            for (int t = 0; t < 4; ++t) {
                const double yv = (acc[t] + cbv) * inv + shift;
                const double h  = v + (yv - v) * tau;
                const double sp = (h >= 1.0) ? 1.0 : 0.0;
                v = h * (1.0 - sp);
                if (OM == 0) {
                    SOUT[(size_t)t * per_t + idx0] = (u8)sp;
                } else if (OM == 1) {
                    const size_t idx = (size_t)t * per_t + idx0;
                    out[idx] = (float)((double)xres[idx] + (double)sres[idx] + sp);
                } else {       // OM==2: u8 frag spike
                    const size_t fa = (((size_t)(jt * nkbo + (o >> 5)) * 4 + t) << 9)
                                    + (size_t)((jl + (((o & 31) >> 3) << 4)) << 3)
                                    + (o & 7);
                    SOUT[fa] = (u8)sp;
                }
            }
        }
    }
}

// ---------------------------------------------------------------------------
// Spike attention + fused LIF (exact dyadic arithmetic, r5-r19 proven math).
// r20: n-split NS=4 (grid B*NH*4) — each block recomputes kv (exact, full N)
// and runs att+LIF on its 49-column slice.  Bit-identical outputs.
// ---------------------------------------------------------------------------
__global__ __launch_bounds__(256) void attn_lif_kernel(
    const u8* __restrict__ SQ, const u8* __restrict__ SK, const u8* __restrict__ SV,
    u8* __restrict__ SATT, const float* __restrict__ lw)
{
    __shared__ u8 q_lds[DH_ * NSLC];      // 1568 B (slice only)
    __shared__ u8 k_lds[DH_ * N_];        // 6272 B (full)
    __shared__ u8 v_lds[DH_ * N_];
    __shared__ float kv_lds[DH_ * DH_];   // 4 KB
    __shared__ float vstate[DH_ * NSLC];  // 6.3 KB (slice only)
    const int tid = threadIdx.x;
    const int slc = blockIdx.x & 3;
    const int bh  = blockIdx.x >> 2;
    const int b = bh / NH_, h = bh % NH_;
    const int n0 = slc * NSLC;
    const float tau = 1.0f / (1.0f + expf(-lw[0]));

    for (int i = tid; i < DH_ * NSLC; i += 256) vstate[i] = 0.0f;

    for (int t = 0; t < T_; ++t) {
        const size_t base = ((size_t)((t * B_ + b) * C_) + h * DH_) * N_;
        __syncthreads();
        for (int i = tid; i < DH_ * N_ / 4; i += 256) {
            ((unsigned int*)k_lds)[i] = ((const unsigned int*)(SK + base))[i];
            ((unsigned int*)v_lds)[i] = ((const unsigned int*)(SV + base))[i];
        }
        for (int i = tid; i < DH_ * NSLC; i += 256) {
            const int row = i / NSLC, col = i % NSLC;
            q_lds[i] = SQ[base + (size_t)row * N_ + n0 + col];
        }
        __syncthreads();

#pragma unroll
        for (int r = 0; r < 4; ++r) {
            const int e = tid + 256 * r;
            const int i = e >> 5, jj = e & 31;
            int s = 0;
            for (int nn = 0; nn < N_; nn += 4) {
                uchar4 kk = *(const uchar4*)&k_lds[i * N_ + nn];
                uchar4 uv = *(const uchar4*)&v_lds[jj * N_ + nn];
                s += kk.x * uv.x + kk.y * uv.y + kk.z * uv.z + kk.w * uv.w;
            }
            kv_lds[e] = (float)s;
        }
        __syncthreads();

        for (int e = tid; e < DH_ * NSLC; e += 256) {
            const int jj = e / NSLC, nn = e % NSLC;
            float s = 0.0f;
#pragma unroll
            for (int i = 0; i < DH_; ++i)
                s += q_lds[i * NSLC + nn] ? kv_lds[i * DH_ + jj] : 0.0f;
            const float att = 0.125f * s;
            const float v = vstate[e];
            const float hh = v + (att - v) * tau;
            const float sp = (hh >= 1.0f) ? 1.0f : 0.0f;
            vstate[e] = hh * (1.0f - sp);
            SATT[base + (size_t)jj * N_ + n0 + nn] = (u8)sp;
        }
    }
}

// ---------------------------------------------------------------------------
extern "C" void kernel_launch(void* const* d_in, const int* in_sizes, int n_in,
                              void* d_out, int out_size, void* d_ws, size_t ws_size,
                              hipStream_t stream)
{
    const float* x       = (const float*)d_in[0];
    const float* q_w     = (const float*)d_in[1];
    const float* q_bn    = (const float*)d_in[2];
    const float* q_lw    = (const float*)d_in[3];
    const float* k_w     = (const float*)d_in[4];
    const float* k_bn    = (const float*)d_in[5];
    const float* k_lw    = (const float*)d_in[6];
    const float* v_w     = (const float*)d_in[7];
    const float* v_bn    = (const float*)d_in[8];
    const float* v_lw    = (const float*)d_in[9];
    const float* attn_lw = (const float*)d_in[10];
    const float* proj_w  = (const float*)d_in[11];
    const float* proj_b  = (const float*)d_in[12];
    const float* proj_bn = (const float*)d_in[13];
    const float* proj_lw = (const float*)d_in[14];
    const float* fc1_w   = (const float*)d_in[15];
    const float* fc1_b   = (const float*)d_in[16];
    const float* fc1_bn  = (const float*)d_in[17];
    const float* fc1_lw  = (const float*)d_in[18];
    const float* fc2_w   = (const float*)d_in[19];
    const float* fc2_b   = (const float*)d_in[20];
    const float* fc2_bn  = (const float*)d_in[21];
    const float* fc2_lw  = (const float*)d_in[22];

    // ---- workspace layout (~144 MB), phase-aliased (r19-proven) ----
    u8* base = (u8*)d_ws;
    float* XTf32   = (float*)(base);                // [0, 38.5M)      ph1..fc1fix
    short* XTfr    = (short*)(base + 38535168);     // [38.5, 77.07M)  ph1 & ph4 (bf16 hi/lo frags)
    u8*    SQ      = base + 77070336;               // ph1-2
    u8*    SK      = base + 86704128;
    u8*    SV      = base + 96337920;
    u8*    SATT    = base + 105971712;              // ph2-3, ends 115.6M
    u8*    SZfrag  = base + 77070336;               // ph4-5 overlay (38.5M u8 frags)
    u8*    SATTfr  = base + 115605504;              // 9.6M u8 frags, ph3
    u8*    SPT     = base + 115605504;              // 9.6M linear-T u8, ph4 overlay
    u8*    SP      = base + 125239296;              // 9.6M, ph3-5
    u32*   cnt     = (u32*)(base + 134873088);      // 256 B
    u32*   flags   = (u32*)(base + 134873344);      // 2.1M
    short* WAb     = (short*)(base + 136970496);    // 7.08M -> ends ~144.0M
    float* out = (float*)d_out;

    short *WAq = WAb,           *WAk = WAb + 294912, *WAv = WAb + 589824,
          *WAp = WAb + 884736,  *WA1 = WAb + 1179648, *WA2 = WAb + 2359296;
    u32 *flQ = flags, *flP = flags + FCAP, *fl1 = flags + 2 * FCAP, *fl2 = flags + 3 * FCAP;

    // 0. single prologue dispatch: all 6 weight splits + counter zeroing
    wprep_all<<<864, 256, 0, stream>>>(q_w, k_w, v_w, proj_w, fc1_w, fc2_w,
                                       WAq, WAk, WAv, WAp, WA1, WA2, cnt);

    // 1. x -> frags + exact linear XTf32; fused q/k/v GEMM+LIF; fixup
    tpose<0><<<128 * 6, 256, 0, stream>>>(x, nullptr, XTfr, XTf32, nullptr, C_, 6);
    gemm_lif<2, 0, 3, 64><<<98 * 6 * 3, 256, 0, stream>>>(
        XTfr, WAq, WAk, WAv,
        nullptr, nullptr, nullptr, q_bn, k_bn, v_bn, q_lw, k_lw, v_lw,
        SQ, SK, SV, nullptr, nullptr, nullptr, cnt + 0, flQ, C_, C_, 6);
    fixup_t<0, 0><<<512, 256, 0, stream>>>(
        XTf32, nullptr, q_w, k_w, v_w, nullptr, nullptr, nullptr,
        q_bn, k_bn, v_bn, q_lw, k_lw, v_lw,
        SQ, SK, SV, nullptr, nullptr, nullptr, cnt + 0, flQ, C_, C_);

    // 2. attention + LIF (exact), n-split x4
    attn_lif_kernel<<<B_ * NH_ * 4, 256, 0, stream>>>(SQ, SK, SV, SATT, attn_lw);

    // 3. proj: SATT -> u8 frags; GEMM (u8-B, OT=32, grid 1176); fixup
    tpose<1><<<128 * 6, 256, 0, stream>>>(SATT, nullptr, SATTfr, nullptr, nullptr, C_, 6);
    gemm_lif<1, 0, 1, 32><<<98 * 12, 256, 0, stream>>>(
        SATTfr, WAp, WAp, WAp,
        proj_b, proj_b, proj_b, proj_bn, proj_bn, proj_bn, proj_lw, proj_lw, proj_lw,
        SP, SP, SP, nullptr, nullptr, nullptr, cnt + 1, flP, C_, C_, 12);
    fixup_t<1, 0><<<512, 256, 0, stream>>>(
        SATTfr, nullptr, proj_w, proj_w, proj_w, proj_b, proj_b, proj_b,
        proj_bn, proj_bn, proj_bn, proj_lw, proj_lw, proj_lw,
        SP, SP, SP, nullptr, nullptr, nullptr, cnt + 1, flP, C_, C_);

    // 4. fc1: (x+SP) -> frags + SPT; GEMM writes SZfrag u8 directly (OM=2); fixup
    tpose<0><<<128 * 6, 256, 0, stream>>>(x, SP, XTfr, nullptr, SPT, C_, 6);
    gemm_lif<2, 2, 1, 64><<<98 * 24, 256, 0, stream>>>(
        XTfr, WA1, WA1, WA1,
        fc1_b, fc1_b, fc1_b, fc1_bn, fc1_bn, fc1_bn, fc1_lw, fc1_lw, fc1_lw,
        SZfrag, SZfrag, SZfrag, nullptr, nullptr, nullptr, cnt + 2, fl1, HID_, C_, 24);
    fixup_t<2, 2><<<512, 256, 0, stream>>>(
        XTf32, SPT, fc1_w, fc1_w, fc1_w, fc1_b, fc1_b, fc1_b,
        fc1_bn, fc1_bn, fc1_bn, fc1_lw, fc1_lw, fc1_lw,
        SZfrag, SZfrag, SZfrag, nullptr, nullptr, nullptr, cnt + 2, fl1, HID_, C_);

    // 5. fc2 (OT=32, grid 1176): reads SZfrag u8; GEMM -> final f32 out; fixup
    gemm_lif<1, 1, 1, 32><<<98 * 12, 256, 0, stream>>>(
        SZfrag, WA2, WA2, WA2,
        fc2_b, fc2_b, fc2_b, fc2_bn, fc2_bn, fc2_bn, fc2_lw, fc2_lw, fc2_lw,
        nullptr, nullptr, nullptr, x, SP, out, cnt + 3, fl2, C_, HID_, 12);
    fixup_t<1, 1><<<512, 256, 0, stream>>>(
        SZfrag, nullptr, fc2_w, fc2_w, fc2_w, fc2_b, fc2_b, fc2_b,
        fc2_bn, fc2_bn, fc2_bn, fc2_lw, fc2_lw, fc2_lw,
        nullptr, nullptr, nullptr, x, SP, out, cnt + 3, fl2, C_, HID_);
}

// Round 21
// 837.030 us; speedup vs baseline: 1.1135x; 1.0102x over previous
//
#include <hip/hip_runtime.h>
#include <math.h>

#define T_   4
#define B_   32
#define C_   384
#define N_   196
#define HID_ 1536
#define NH_  12
#define DH_  32
#define NCOL (B_*N_)            // 6272 columns j=(b,n)
#define NJT  (NCOL/16)          // 392 j-tiles of 16
#define NSLC 49                 // attn n-slice (N_/4)
#define THRESH 2e-3f            // certainty margin (worst-case MFMA-path err ~3e-4)
#define FCAP (1u<<17)

typedef unsigned char u8;
typedef unsigned int  u32;
typedef unsigned long long u64;
using bf16x8 = __attribute__((ext_vector_type(8))) short;
using f32x4  = __attribute__((ext_vector_type(4))) float;

__device__ __forceinline__ float bfbits2f(short u) {
    union { u32 i; float f; } c; c.i = ((u32)(unsigned short)u) << 16; return c.f;
}
__device__ __forceinline__ short f2bf(float f) {       // RNE f32 -> bf16 bits
    u32 b = __float_as_uint(f);
    return (short)((b + 0x7FFFu + ((b >> 16) & 1u)) >> 16);
}
// u8 spikes (0/1) -> exact bf16 bits (0x0000 / 0x3F80)
__device__ __forceinline__ bf16x8 u8x8_to_bf16(uint2 raw) {
    short s[8];
#pragma unroll
    for (int k = 0; k < 4; ++k) {
        s[k]     = ((raw.x >> (8 * k)) & 0xFFu) ? (short)0x3F80 : (short)0;
        s[k + 4] = ((raw.y >> (8 * k)) & 0xFFu) ? (short)0x3F80 : (short)0;
    }
    return *(bf16x8*)s;
}

__device__ __forceinline__ void gload_lds16(const short* g, short* l) {
    __builtin_amdgcn_global_load_lds(
        (const __attribute__((address_space(1))) void*)g,
        (__attribute__((address_space(3))) void*)l, 16, 0, 0);
}

// ---------------------------------------------------------------------------
// Single prologue dispatch (r20): all 6 weight splits (fragment-major,
// hi/lo adjacent) + counter zeroing, selected by blockIdx range.
// ---------------------------------------------------------------------------
__global__ void wprep_all(
    const float* __restrict__ qw, const float* __restrict__ kw,
    const float* __restrict__ vw, const float* __restrict__ pw,
    const float* __restrict__ w1, const float* __restrict__ w2,
    short* __restrict__ WAq, short* __restrict__ WAk, short* __restrict__ WAv,
    short* __restrict__ WAp, short* __restrict__ WA1, short* __restrict__ WA2,
    u32* __restrict__ cnt)
{
    if (blockIdx.x == 0 && threadIdx.x < 4) cnt[threadIdx.x] = 0;
    const int b = blockIdx.x;
    const float* W; short* HL; int c_out, c_in, b0;
    if      (b < 72)  { W = qw; HL = WAq; c_out = C_;   c_in = C_;   b0 = 0;   }
    else if (b < 144) { W = kw; HL = WAk; c_out = C_;   c_in = C_;   b0 = 72;  }
    else if (b < 216) { W = vw; HL = WAv; c_out = C_;   c_in = C_;   b0 = 144; }
    else if (b < 288) { W = pw; HL = WAp; c_out = C_;   c_in = C_;   b0 = 216; }
    else if (b < 576) { W = w1; HL = WA1; c_out = HID_; c_in = C_;   b0 = 288; }
    else              { W = w2; HL = WA2; c_out = C_;   c_in = HID_; b0 = 576; }

    const int ng = c_out * (c_in >> 3);
    int i = (b - b0) * 256 + threadIdx.x;
    if (i >= ng) return;
    const int o = i / (c_in >> 3);
    const int c = (i % (c_in >> 3)) << 3;
    const int ot = o >> 4, ol = o & 15;
    const int kb = c >> 5, part = (c & 31) >> 3;
    const int nkb = c_in >> 5;
    const size_t fp = (((size_t)(ot * nkb + kb) * 2) << 9) + (size_t)((ol + (part << 4)) << 3);
    short h8[8], l8[8];
#pragma unroll
    for (int k = 0; k < 8; ++k) {
        float f = W[(size_t)o * c_in + c + k];
        short h = f2bf(f);
        h8[k] = h;
        l8[k] = f2bf(f - bfbits2f(h));
    }
    *(bf16x8*)&HL[fp]       = *(bf16x8*)h8;
    *(bf16x8*)&HL[fp + 512] = *(bf16x8*)l8;
}

// ---------------------------------------------------------------------------
// Transpose [tb][c][n] -> fragment-major B superchunks (MODE 0 only now):
// f32 (+optional u8 Sadd) -> bf16 hi/lo frags (r14 layout) + optional exact
// linear f32 F and u8 SPT copies.
// ---------------------------------------------------------------------------
__global__ __launch_bounds__(256) void tpose0(
    const float* __restrict__ Xf, const u8* __restrict__ Sadd,
    short* __restrict__ HL,
    float* __restrict__ F, u8* __restrict__ SPTo,
    int c_tot, int nct)
{
    __shared__ float lds[64][197];
    __shared__ u8 slds[64][197];
    const int tid = threadIdx.x;
    const int tb = blockIdx.x / nct;
    const int ct = blockIdx.x % nct;
    const int t = tb / B_, b = tb % B_;
    const int nkb = c_tot >> 5;

    for (int i = tid; i < 64 * N_; i += 256) {
        int c = i / N_, n = i % N_;
        size_t g = ((size_t)tb * c_tot + ct * 64 + c) * N_ + n;
        float v = Xf[g];
        u8 s = Sadd ? Sadd[g] : (u8)0;
        lds[c][n] = v + (float)s;
        slds[c][n] = s;
    }
    __syncthreads();

    for (int i = tid; i < N_ * 8; i += 256) {
        const int n = i >> 3;
        const int c_loc = (i & 7) << 3;
        const int c = ct * 64 + c_loc;
        const int j = b * N_ + n;
        const int jt = j >> 4, jl = j & 15;
        const int kb = c >> 5, part = (c & 31) >> 3;
        const size_t pos = (size_t)((jl + (part << 4)) << 3);
        short h8[8], l8[8];
        float f8[8];
#pragma unroll
        for (int k = 0; k < 8; ++k) {
            float f = lds[c_loc + k][n];
            f8[k] = f;
            short h = f2bf(f);
            h8[k] = h;
            l8[k] = f2bf(f - bfbits2f(h));
        }
        const size_t fp = (((size_t)(jt * nkb + kb) * 8 + t * 2) << 9) + pos;
        *(bf16x8*)&HL[fp]       = *(bf16x8*)h8;
        *(bf16x8*)&HL[fp + 512] = *(bf16x8*)l8;
        if (F) {
            const size_t lp = ((size_t)(t * NCOL + j)) * c_tot + c;
            *(float4*)&F[lp]     = *(float4*)&f8[0];
            *(float4*)&F[lp + 4] = *(float4*)&f8[4];
        }
        if (SPTo) {
            const size_t lp = ((size_t)(t * NCOL + j)) * c_tot + c;
#pragma unroll
            for (int k = 0; k < 8; ++k) SPTo[lp + k] = slds[c_loc + k][n];
        }
    }
}

// ---------------------------------------------------------------------------
// MFMA GEMM + BN + LIF + flagging.  C[o,j,t] = sum_c W[o,c] X[t,j,c].
// r18 occupancy-first structure (64-reg acc, no B ping/pong, lb(256,4)).
// OT: o-tile 64 or 32.  SPLITS=1 B = u8 frags + in-reg convert.
// OM: 0 = row-major u8 spikes; 1 = final f32 (xres+sres+spike);
//     2 = u8-frag spikes (direct frag write).
// D: col = lane&15, row = (lane>>4)*4 + reg  [m89-verified].
// ---------------------------------------------------------------------------
template<int SPLITS, int OM, int NZ, int OT>
__global__ __launch_bounds__(256, 4) void gemm_lif(
    const void* __restrict__ BHL,
    const short* __restrict__ WA0, const short* __restrict__ WA1, const short* __restrict__ WA2,
    const float* __restrict__ cb0, const float* __restrict__ cb1, const float* __restrict__ cb2,
    const float* __restrict__ bn0, const float* __restrict__ bn1, const float* __restrict__ bn2,
    const float* __restrict__ lw0, const float* __restrict__ lw1, const float* __restrict__ lw2,
    u8* S0, u8* S1, u8* S2,
    const float* __restrict__ xres, const u8* __restrict__ sres, float* __restrict__ out,
    u32* __restrict__ cnt, u32* __restrict__ flags,
    int c_out, int c_in, int nob)
{
    constexpr int NOS = OT / 16;                 // o-subtiles per thread (4 or 2)
    __shared__ short a_lds[2][NOS * 2][512];     // 16 KB (OT=64) / 8 KB (OT=32)
    const int tid = threadIdx.x;
    const int w = tid >> 6, l = tid & 63;

    // ---- bijective XCD-contiguity swizzle (8 XCDs, m204 formula) ----
    const u32 nwg = gridDim.x;
    const u32 q = nwg >> 3, r = nwg & 7;
    const u32 xcd = blockIdx.x & 7, off = blockIdx.x >> 3;
    const u32 id = (xcd < r ? xcd * (q + 1) : r * (q + 1) + (xcd - r) * q) + off;

    const int mt  = (int)(id / (u32)(nob * NZ));
    const int rem = (int)(id % (u32)(nob * NZ));
    const int z  = (NZ == 1) ? 0 : (rem % NZ);
    const int ob = (NZ == 1) ? rem : (rem / NZ);

    const short* WA  = (z == 0) ? WA0 : ((z == 1) ? WA1 : WA2);
    const float* cb  = (z == 0) ? cb0 : ((z == 1) ? cb1 : cb2);
    const float* bnp = (z == 0) ? bn0 : ((z == 1) ? bn1 : bn2);
    const float* lw  = (z == 0) ? lw0 : ((z == 1) ? lw1 : lw2);
    u8* SOUT         = (z == 0) ? S0  : ((z == 1) ? S1  : S2);

    const int nkb = c_in >> 5;
    const int jt = mt * 4 + w;
    const int j  = jt * 16 + (l & 15);
    const int obBase = ob * OT;

    f32x4 acc[4][NOS];
#pragma unroll
    for (int t = 0; t < 4; ++t)
#pragma unroll
        for (int os = 0; os < NOS; ++os)
            acc[t][os] = (f32x4){0.f, 0.f, 0.f, 0.f};

    const short* bbase16 = (const short*)BHL + (size_t)l * 8;   // SPLITS=2
    const u8*    bbase8  = (const u8*)BHL + (size_t)l * 8;      // SPLITS=1

    bf16x8 bh[4], bl[4];

    auto LOADB = [&](int kb) {
#pragma unroll
        for (int t = 0; t < 4; ++t) {
            if (SPLITS == 2) {
                const short* p = bbase16 + (((size_t)jt * nkb + kb) << 12);
                bh[t] = *(const bf16x8*)(p + ((size_t)(t * 2)     << 9));
                bl[t] = *(const bf16x8*)(p + ((size_t)(t * 2 + 1) << 9));
            } else {
                const u8* p = bbase8 + (((size_t)jt * nkb + kb) << 11);
                bh[t] = u8x8_to_bf16(*(const uint2*)(p + ((size_t)t << 9)));
            }
        }
    };
    // stage A(kb): NOS*2 chunks of 1KB; wave w stages NOS/2 of them
    auto STAGE = [&](int kb, int p) {
#pragma unroll
        for (int cc = 0; cc < NOS / 2; ++cc) {
            const int ch = w * (NOS / 2) + cc;
            const int os = ch >> 1, split = ch & 1;
            const short* src = WA
                + ((((size_t)(ob * NOS + os) * nkb + kb) * 2 + split) << 9) + (size_t)l * 8;
            gload_lds16(src, &a_lds[p][ch][(size_t)l * 8]);
        }
    };
    auto COMPUTE = [&](int p) {
#pragma unroll
        for (int os = 0; os < NOS; ++os) {
            const bf16x8 ah = *(const bf16x8*)&a_lds[p][os * 2][(size_t)l * 8];
            const bf16x8 al = *(const bf16x8*)&a_lds[p][os * 2 + 1][(size_t)l * 8];
#pragma unroll
            for (int t = 0; t < 4; ++t) {
                acc[t][os] = __builtin_amdgcn_mfma_f32_16x16x32_bf16(ah, bh[t], acc[t][os], 0, 0, 0);
                acc[t][os] = __builtin_amdgcn_mfma_f32_16x16x32_bf16(al, bh[t], acc[t][os], 0, 0, 0);
                if (SPLITS == 2)   // lo x lo term dropped (r11)
                    acc[t][os] = __builtin_amdgcn_mfma_f32_16x16x32_bf16(ah, bl[t], acc[t][os], 0, 0, 0);
            }
        }
    };

    STAGE(0, 0);
    __syncthreads();                       // buf0 ready
    for (int kb = 0; kb < nkb; ++kb) {
        const int p = kb & 1;
        if (kb + 1 < nkb) STAGE(kb + 1, p ^ 1);
        LOADB(kb);
        COMPUTE(p);
        __syncthreads();                   // next buf ready; this buf free
    }

    const float tau = 1.0f / (1.0f + expf(-lw[0]));
    const size_t per_t = (size_t)B_ * c_out * N_;
    const int jb = j / N_, jn = j % N_;
    const int nkbo = c_out >> 5;           // for OM==2 frag writes
#pragma unroll
    for (int os = 0; os < NOS; ++os) {
#pragma unroll
        for (int r2 = 0; r2 < 4; ++r2) {
            const int o = obBase + os * 16 + (l >> 4) * 4 + r2;
            const float g  = bnp[o];
            const float be = bnp[c_out + o];
            const float mm = bnp[2 * c_out + o];
            const float vv = bnp[3 * c_out + o];
            const float inv   = g / sqrtf(vv + 1e-5f);
            const float shift = be - mm * inv;
            const float cbv   = cb ? cb[o] : 0.0f;
            const size_t idx0 = ((size_t)jb * c_out + o) * N_ + jn;
            float v = 0.0f;
            bool flag = false;
#pragma unroll
            for (int t = 0; t < 4; ++t) {
                const float yv = (acc[t][os][r2] + cbv) * inv + shift;
                const float h  = v + (yv - v) * tau;
                const float sp = (h >= 1.0f) ? 1.0f : 0.0f;
                flag = flag || (fabsf(h - 1.0f) < THRESH);
                v = h * (1.0f - sp);
                if (OM == 0) {
                    SOUT[(size_t)t * per_t + idx0] = (u8)sp;
                } else if (OM == 1) {
                    const size_t idx = (size_t)t * per_t + idx0;
                    out[idx] = (float)((double)xres[idx] + (double)sres[idx] + (double)sp);
                } else {       // OM==2: u8 frag spike (SPL=1 layout)
                    const size_t fa = (((size_t)(jt * nkbo + (o >> 5)) * 4 + t) << 9)
                                    + (size_t)(((l & 15) + (((o & 31) >> 3) << 4)) << 3)
                                    + (o & 7);
                    SOUT[fa] = (u8)sp;
                }
            }
            if (flag) {
                u32 p2 = atomicAdd(cnt, 1u);
                if (p2 < FCAP) flags[p2] = ((u32)(z * c_out + o)) * (u32)NCOL + (u32)j;
            }
        }
    }
}

// ---------------------------------------------------------------------------
// f64 fixup (decision math = r5/r7-proven all-f64 path).
// IN_MODE 0: linear f32 XT; 1: u8 frag spikes (r19 layout); 2: f32 XT + SPT.
// OM 0: row-major u8 spikes; 1: final f32; 2: u8-frag spikes.
// ---------------------------------------------------------------------------
template<int IN_MODE, int OM>
__global__ __launch_bounds__(256) void fixup_t(
    const void* __restrict__ XT, const u8* __restrict__ SPT,
    const float* __restrict__ W0, const float* __restrict__ W1, const float* __restrict__ W2,
    const float* __restrict__ cb0, const float* __restrict__ cb1, const float* __restrict__ cb2,
    const float* __restrict__ bn0, const float* __restrict__ bn1, const float* __restrict__ bn2,
    const float* __restrict__ lw0, const float* __restrict__ lw1, const float* __restrict__ lw2,
    u8* S0, u8* S1, u8* S2,
    const float* __restrict__ xres, const u8* __restrict__ sres, float* out,
    const u32* __restrict__ cnt, const u32* __restrict__ flags,
    int c_out, int c_in)
{
    const int lane = threadIdx.x & 63;
    const int wid  = (blockIdx.x * 256 + threadIdx.x) >> 6;
    const int nw   = (gridDim.x * 256) >> 6;
    u32 nrec = *cnt;
    if (nrec > FCAP) nrec = FCAP;

    const float* XTf = (const float*)XT;
    const u8*    XT8 = (const u8*)XT;
    const int nkb = c_in >> 5;
    const int nkbo = c_out >> 5;

    for (u32 r = wid; r < nrec; r += nw) {
        const u32 rec = flags[r];
        const int j  = (int)(rec % (u32)NCOL);
        const u32 zo = rec / (u32)NCOL;
        const int z  = (int)(zo / (u32)c_out);
        const int o  = (int)(zo % (u32)c_out);
        const int jt = j >> 4, jl = j & 15;

        const float* W   = (z == 0) ? W0  : ((z == 1) ? W1  : W2);
        const float* cb  = (z == 0) ? cb0 : ((z == 1) ? cb1 : cb2);
        const float* bnp = (z == 0) ? bn0 : ((z == 1) ? bn1 : bn2);
        const float* lw  = (z == 0) ? lw0 : ((z == 1) ? lw1 : lw2);
        u8* SOUT         = (z == 0) ? S0  : ((z == 1) ? S1  : S2);

        double acc[4] = {0.0, 0.0, 0.0, 0.0};
        for (int c = lane; c < c_in; c += 64) {
            const double w = (double)W[(size_t)o * c_in + c];
#pragma unroll
            for (int t = 0; t < 4; ++t) {
                double xval;
                if (IN_MODE == 1) {
                    const int kb = c >> 5, part = (c & 31) >> 3, elem = c & 7;
                    const size_t idx = (((size_t)(jt * nkb + kb) * 4 + t) << 9)
                                     + (size_t)((jl + (part << 4)) << 3) + elem;
                    xval = (double)XT8[idx];
                } else {
                    const size_t i = ((size_t)(t * NCOL + j)) * c_in + c;
                    if (IN_MODE == 0) xval = (double)XTf[i];
                    else              xval = (double)XTf[i] + (double)SPT[i];
                }
                acc[t] = fma(w, xval, acc[t]);
            }
        }
#pragma unroll
        for (int m = 32; m; m >>= 1) {
#pragma unroll
            for (int t = 0; t < 4; ++t)
                acc[t] += __shfl_xor(acc[t], m, 64);
        }

        if (lane == 0) {
            const double tau = 1.0 / (1.0 + exp(-(double)lw[0]));
            const double g  = (double)bnp[o];
            const double be = (double)bnp[c_out + o];
            const double mm = (double)bnp[2 * c_out + o];
            const double vv = (double)bnp[3 * c_out + o];
            const double inv   = g / sqrt(vv + 1e-5);
            const double shift = be - mm * inv;
            const double cbv   = cb ? (double)cb[o] : 0.0;
            const size_t per_t = (size_t)B_ * c_out * N_;
            const int jb = j / N_, jn = j % N_;
            const size_t idx0  = ((size_t)jb * c_out + o) * N_ + jn;
            double v = 0.0;
#pragma unroll
            for (int t = 0; t < 4; ++t) {
                const double yv = (acc[t] + cbv) * inv + shift;
                const double h  = v + (yv - v) * tau;
                const double sp = (h >= 1.0) ? 1.0 : 0.0;
                v = h * (1.0 - sp);
                if (OM == 0) {
                    SOUT[(size_t)t * per_t + idx0] = (u8)sp;
                } else if (OM == 1) {
                    const size_t idx = (size_t)t * per_t + idx0;
                    out[idx] = (float)((double)xres[idx] + (double)sres[idx] + sp);
                } else {       // OM==2: u8 frag spike
                    const size_t fa = (((size_t)(jt * nkbo + (o >> 5)) * 4 + t) << 9)
                                    + (size_t)((jl + (((o & 31) >> 3) << 4)) << 3)
                                    + (o & 7);
                    SOUT[fa] = (u8)sp;
                }
            }
        }
    }
}

// ---------------------------------------------------------------------------
// Spike attention + fused LIF (exact dyadic arithmetic, r5-r20 proven math).
// n-split NS=4 (r20).  r21: writes u8 FRAGMENTS directly (DH=32 aligns with
// the 32-channel kb granularity: kb = head) — eliminates the SATT row-major
// buffer and the tpose<1> dispatch.  Bit-identical bytes at frag addresses.
// ---------------------------------------------------------------------------
__global__ __launch_bounds__(256) void attn_lif_kernel(
    const u8* __restrict__ SQ, const u8* __restrict__ SK, const u8* __restrict__ SV,
    u8* __restrict__ SATTfr, const float* __restrict__ lw)
{
    __shared__ u8 q_lds[DH_ * NSLC];      // 1568 B (slice only)
    __shared__ u8 k_lds[DH_ * N_];        // 6272 B (full)
    __shared__ u8 v_lds[DH_ * N_];
    __shared__ float kv_lds[DH_ * DH_];   // 4 KB
    __shared__ float vstate[DH_ * NSLC];  // 6.3 KB (slice only)
    const int tid = threadIdx.x;
    const int slc = blockIdx.x & 3;
    const int bh  = blockIdx.x >> 2;
    const int b = bh / NH_, h = bh % NH_;
    const int n0 = slc * NSLC;
    const float tau = 1.0f / (1.0f + expf(-lw[0]));

    for (int i = tid; i < DH_ * NSLC; i += 256) vstate[i] = 0.0f;

    for (int t = 0; t < T_; ++t) {
        const size_t base = ((size_t)((t * B_ + b) * C_) + h * DH_) * N_;
        __syncthreads();
        for (int i = tid; i < DH_ * N_ / 4; i += 256) {
            ((unsigned int*)k_lds)[i] = ((const unsigned int*)(SK + base))[i];
            ((unsigned int*)v_lds)[i] = ((const unsigned int*)(SV + base))[i];
        }
        for (int i = tid; i < DH_ * NSLC; i += 256) {
            const int row = i / NSLC, col = i % NSLC;
            q_lds[i] = SQ[base + (size_t)row * N_ + n0 + col];
        }
        __syncthreads();

#pragma unroll
        for (int r = 0; r < 4; ++r) {
            const int e = tid + 256 * r;
            const int i = e >> 5, jj = e & 31;
            int s = 0;
            for (int nn = 0; nn < N_; nn += 4) {
                uchar4 kk = *(const uchar4*)&k_lds[i * N_ + nn];
                uchar4 uv = *(const uchar4*)&v_lds[jj * N_ + nn];
                s += kk.x * uv.x + kk.y * uv.y + kk.z * uv.z + kk.w * uv.w;
            }
            kv_lds[e] = (float)s;
        }
        __syncthreads();

        for (int e = tid; e < DH_ * NSLC; e += 256) {
            const int jj = e / NSLC, nn = e % NSLC;
            float s = 0.0f;
#pragma unroll
            for (int i = 0; i < DH_; ++i)
                s += q_lds[i * NSLC + nn] ? kv_lds[i * DH_ + jj] : 0.0f;
            const float att = 0.125f * s;
            const float v = vstate[e];
            const float hh = v + (att - v) * tau;
            const float sp = (hh >= 1.0f) ? 1.0f : 0.0f;
            vstate[e] = hh * (1.0f - sp);
            // r21: direct u8 frag write (c = h*32 + jj -> kb = h, part = jj>>3)
            const int j = b * N_ + n0 + nn;
            const int jt = j >> 4, jl = j & 15;
            const size_t fa = (((size_t)(jt * (C_ >> 5) + h) * 4 + t) << 9)
                            + (size_t)((jl + ((jj >> 3) << 4)) << 3) + (jj & 7);
            SATTfr[fa] = (u8)sp;
        }
    }
}

// ---------------------------------------------------------------------------
extern "C" void kernel_launch(void* const* d_in, const int* in_sizes, int n_in,
                              void* d_out, int out_size, void* d_ws, size_t ws_size,
                              hipStream_t stream)
{
    const float* x       = (const float*)d_in[0];
    const float* q_w     = (const float*)d_in[1];
    const float* q_bn    = (const float*)d_in[2];
    const float* q_lw    = (const float*)d_in[3];
    const float* k_w     = (const float*)d_in[4];
    const float* k_bn    = (const float*)d_in[5];
    const float* k_lw    = (const float*)d_in[6];
    const float* v_w     = (const float*)d_in[7];
    const float* v_bn    = (const float*)d_in[8];
    const float* v_lw    = (const float*)d_in[9];
    const float* attn_lw = (const float*)d_in[10];
    const float* proj_w  = (const float*)d_in[11];
    const float* proj_b  = (const float*)d_in[12];
    const float* proj_bn = (const float*)d_in[13];
    const float* proj_lw = (const float*)d_in[14];
    const float* fc1_w   = (const float*)d_in[15];
    const float* fc1_b   = (const float*)d_in[16];
    const float* fc1_bn  = (const float*)d_in[17];
    const float* fc1_lw  = (const float*)d_in[18];
    const float* fc2_w   = (const float*)d_in[19];
    const float* fc2_b   = (const float*)d_in[20];
    const float* fc2_bn  = (const float*)d_in[21];
    const float* fc2_lw  = (const float*)d_in[22];

    // ---- workspace layout (~144 MB), phase-aliased (r19/r20-proven) ----
    u8* base = (u8*)d_ws;
    float* XTf32   = (float*)(base);                // [0, 38.5M)      ph1..fc1fix
    short* XTfr    = (short*)(base + 38535168);     // [38.5, 77.07M)  ph1 & ph4 (bf16 hi/lo frags)
    u8*    SQ      = base + 77070336;               // ph1-2
    u8*    SK      = base + 86704128;
    u8*    SV      = base + 96337920;               // ends 105.97M
    u8*    SZfrag  = base + 77070336;               // ph4-5 overlay (38.5M u8 frags)
    u8*    SATTfr  = base + 115605504;              // 9.6M u8 frags, ph2-3 (attn writes directly)
    u8*    SPT     = base + 115605504;              // 9.6M linear-T u8, ph4 overlay
    u8*    SP      = base + 125239296;              // 9.6M, ph3-5
    u32*   cnt     = (u32*)(base + 134873088);      // 256 B
    u32*   flags   = (u32*)(base + 134873344);      // 2.1M
    short* WAb     = (short*)(base + 136970496);    // 7.08M -> ends ~144.0M
    float* out = (float*)d_out;

    short *WAq = WAb,           *WAk = WAb + 294912, *WAv = WAb + 589824,
          *WAp = WAb + 884736,  *WA1 = WAb + 1179648, *WA2 = WAb + 2359296;
    u32 *flQ = flags, *flP = flags + FCAP, *fl1 = flags + 2 * FCAP, *fl2 = flags + 3 * FCAP;

    // 0. single prologue dispatch: all 6 weight splits + counter zeroing
    wprep_all<<<864, 256, 0, stream>>>(q_w, k_w, v_w, proj_w, fc1_w, fc2_w,
                                       WAq, WAk, WAv, WAp, WA1, WA2, cnt);

    // 1. x -> frags + exact linear XTf32; fused q/k/v GEMM+LIF; fixup
    tpose0<<<128 * 6, 256, 0, stream>>>(x, nullptr, XTfr, XTf32, nullptr, C_, 6);
    gemm_lif<2, 0, 3, 64><<<98 * 6 * 3, 256, 0, stream>>>(
        XTfr, WAq, WAk, WAv,
        nullptr, nullptr, nullptr, q_bn, k_bn, v_bn, q_lw, k_lw, v_lw,
        SQ, SK, SV, nullptr, nullptr, nullptr, cnt + 0, flQ, C_, C_, 6);
    fixup_t<0, 0><<<512, 256, 0, stream>>>(
        XTf32, nullptr, q_w, k_w, v_w, nullptr, nullptr, nullptr,
        q_bn, k_bn, v_bn, q_lw, k_lw, v_lw,
        SQ, SK, SV, nullptr, nullptr, nullptr, cnt + 0, flQ, C_, C_);

    // 2. attention + LIF (exact), n-split x4, writes SATTfr u8 frags directly
    attn_lif_kernel<<<B_ * NH_ * 4, 256, 0, stream>>>(SQ, SK, SV, SATTfr, attn_lw);

    // 3. proj: GEMM (u8-B frags, OT=32); fixup reads SATTfr frags
    gemm_lif<1, 0, 1, 32><<<98 * 12, 256, 0, stream>>>(
        SATTfr, WAp, WAp, WAp,
        proj_b, proj_b, proj_b, proj_bn, proj_bn, proj_bn, proj_lw, proj_lw, proj_lw,
        SP, SP, SP, nullptr, nullptr, nullptr, cnt + 1, flP, C_, C_, 12);
    fixup_t<1, 0><<<512, 256, 0, stream>>>(
        SATTfr, nullptr, proj_w, proj_w, proj_w, proj_b, proj_b, proj_b,
        proj_bn, proj_bn, proj_bn, proj_lw, proj_lw, proj_lw,
        SP, SP, SP, nullptr, nullptr, nullptr, cnt + 1, flP, C_, C_);

    // 4. fc1: (x+SP) -> frags + SPT; GEMM writes SZfrag u8 directly (OM=2); fixup
    tpose0<<<128 * 6, 256, 0, stream>>>(x, SP, XTfr, nullptr, SPT, C_, 6);
    gemm_lif<2, 2, 1, 64><<<98 * 24, 256, 0, stream>>>(
        XTfr, WA1, WA1, WA1,
        fc1_b, fc1_b, fc1_b, fc1_bn, fc1_bn, fc1_bn, fc1_lw, fc1_lw, fc1_lw,
        SZfrag, SZfrag, SZfrag, nullptr, nullptr, nullptr, cnt + 2, fl1, HID_, C_, 24);
    fixup_t<2, 2><<<512, 256, 0, stream>>>(
        XTf32, SPT, fc1_w, fc1_w, fc1_w, fc1_b, fc1_b, fc1_b,
        fc1_bn, fc1_bn, fc1_bn, fc1_lw, fc1_lw, fc1_lw,
        SZfrag, SZfrag, SZfrag, nullptr, nullptr, nullptr, cnt + 2, fl1, HID_, C_);

    // 5. fc2 (OT=32): reads SZfrag u8; GEMM -> final f32 out; fixup
    gemm_lif<1, 1, 1, 32><<<98 * 12, 256, 0, stream>>>(
        SZfrag, WA2, WA2, WA2,
        fc2_b, fc2_b, fc2_b, fc2_bn, fc2_bn, fc2_bn, fc2_lw, fc2_lw, fc2_lw,
        nullptr, nullptr, nullptr, x, SP, out, cnt + 3, fl2, C_, HID_, 12);
    fixup_t<1, 1><<<512, 256, 0, stream>>>(
        SZfrag, nullptr, fc2_w, fc2_w, fc2_w, fc2_b, fc2_b, fc2_b,
        fc2_bn, fc2_bn, fc2_bn, fc2_lw, fc2_lw, fc2_lw,
        nullptr, nullptr, nullptr, x, SP, out, cnt + 3, fl2, C_, HID_);
}